// Round 2
// baseline (913.803 us; speedup 1.0000x reference)
//
#include <hip/hip_runtime.h>
#include <hip/hip_bf16.h>
#include <cstdint>
#include <cstddef>

#define NPLANE 262144      // 512*512
#define SBLK 64            // samples per block
#define STR 148            // LDS activation row stride (floats), padded

typedef unsigned int uint;

__device__ __forceinline__ float blo(uint u){ union{uint i; float f;} v; v.i = u<<16; return v.f; }
__device__ __forceinline__ float bhi(uint u){ union{uint i; float f;} v; v.i = u & 0xffff0000u; return v.f; }

// ---------------- transpose feat (3,48,512,512) fp32 -> (3,512,512,48) bf16 ----------------
__global__ __launch_bounds__(256) void transpose_feat_k(const float* __restrict__ feat,
                                                        unsigned short* __restrict__ featT){
    __shared__ unsigned short lb[256*50];   // 50-ushort padded rows (bank spread)
    const int tid = threadIdx.x;
    const int pos = blockIdx.x*256 + tid;   // (p,y,x) linear, 786432 total
    const int p  = pos >> 18;
    const int yx = pos & (NPLANE-1);
    const float* src = feat + (size_t)p*48*NPLANE + yx;
    #pragma unroll 4
    for (int c = 0; c < 48; ++c){
        float v = src[(size_t)c*NPLANE];            // lanes: consecutive yx -> coalesced
        __hip_bfloat16 h = __float2bfloat16(v);
        lb[tid*50 + c] = *reinterpret_cast<unsigned short*>(&h);
    }
    __syncthreads();
    // block output region: 256 samples * 48 ushorts * 2B = 24576B = 1536 uint4, coalesced
    uint4* dst = (uint4*)(featT + (size_t)blockIdx.x*(256*48));
    #pragma unroll
    for (int m = 0; m < 6; ++m){
        const int u4 = tid + m*256;
        const int byteoff = u4*16;
        const int smp = byteoff/96;
        const int off = (byteoff%96) >> 2;
        const uint* rw = (const uint*)(lb + smp*50);
        uint4 val; val.x = rw[off]; val.y = rw[off+1]; val.z = rw[off+2]; val.w = rw[off+3];
        dst[u4] = val;
    }
}

// ---------------- fused sample + PE + MLP ----------------
template<int K4, int KTAIL>
__device__ __forceinline__ void mlp_layer(float (*Hs)[STR], const float* __restrict__ W,
                                          const float* __restrict__ B, int tid){
    const int tx = tid & 31, ty = tid >> 5;
    const int s0 = ty*8, j0 = tx*4;
    float acc[8][4];
    #pragma unroll
    for (int i=0;i<8;++i){ acc[i][0]=0.f; acc[i][1]=0.f; acc[i][2]=0.f; acc[i][3]=0.f; }
    for (int kk = 0; kk < K4; ++kk){
        const int k = kk*4;
        const float4 wa = *(const float4*)(W + (size_t)(k+0)*128 + j0);
        const float4 wb = *(const float4*)(W + (size_t)(k+1)*128 + j0);
        const float4 wc = *(const float4*)(W + (size_t)(k+2)*128 + j0);
        const float4 wd = *(const float4*)(W + (size_t)(k+3)*128 + j0);
        #pragma unroll
        for (int i=0;i<8;++i){
            const float4 h = *(const float4*)&Hs[s0+i][k];   // broadcast within half-wave
            acc[i][0] += h.x*wa.x + h.y*wb.x + h.z*wc.x + h.w*wd.x;
            acc[i][1] += h.x*wa.y + h.y*wb.y + h.z*wc.y + h.w*wd.y;
            acc[i][2] += h.x*wa.z + h.y*wb.z + h.z*wc.z + h.w*wd.z;
            acc[i][3] += h.x*wa.w + h.y*wb.w + h.z*wc.w + h.w*wd.w;
        }
    }
    #pragma unroll
    for (int t=0;t<KTAIL;++t){
        const int k = K4*4+t;
        const float4 wa = *(const float4*)(W + (size_t)k*128 + j0);
        #pragma unroll
        for (int i=0;i<8;++i){
            const float h = Hs[s0+i][k];
            acc[i][0] += h*wa.x; acc[i][1] += h*wa.y; acc[i][2] += h*wa.z; acc[i][3] += h*wa.w;
        }
    }
    const float4 bb = *(const float4*)(B + j0);
    __syncthreads();            // all reads of old activations complete
    #pragma unroll
    for (int i=0;i<8;++i){
        float4 o;
        o.x = fmaxf(acc[i][0]+bb.x, 0.f);
        o.y = fmaxf(acc[i][1]+bb.y, 0.f);
        o.z = fmaxf(acc[i][2]+bb.z, 0.f);
        o.w = fmaxf(acc[i][3]+bb.w, 0.f);
        *(float4*)&Hs[s0+i][j0] = o;   // in-place: next layer input
    }
    __syncthreads();
}

__global__ __launch_bounds__(256) void nerf_fused(
    const float* __restrict__ x, const float* __restrict__ d,
    const float* __restrict__ feat, const unsigned short* __restrict__ featT,
    const float* __restrict__ W0, const float* __restrict__ b0,
    const float* __restrict__ W1, const float* __restrict__ b1,
    const float* __restrict__ W2, const float* __restrict__ b2,
    const float* __restrict__ W3, const float* __restrict__ b3,
    float* __restrict__ out, int useT)
{
    __shared__ float Hs[SBLK][STR];     // activations, rows=samples (~37 KB)
    __shared__ uint4  sA[3][SBLK];      // 4 corner addrs per (plane,sample)
    __shared__ float4 sW[3][SBLK];      // 4 corner weights

    const int tid = threadIdx.x;
    const int g0 = blockIdx.x * SBLK;   // 64 samples = half a ray -> d uniform

    // ---- phase 1: bilinear params per (sample, plane) ----
    if (tid < 192){
        const int s = tid & 63, p = tid >> 6;
        const int g = g0 + s;
        const float xn0 = x[3*g+0]/3.0f, xn1 = x[3*g+1]/3.0f, xn2 = x[3*g+2]/3.0f;
        const float gx = (p==1)? xn1 : xn0;
        const float gy = (p==0)? xn1 : xn2;
        const float ix = ((gx+1.0f)*0.5f)*511.0f;
        const float iy = ((gy+1.0f)*0.5f)*511.0f;
        const float fx0 = floorf(ix), fy0 = floorf(iy);
        const float wx1 = ix - fx0, wy1 = iy - fy0;
        const float wx0 = 1.0f-wx1, wy0 = 1.0f-wy1;
        const int x0i = (int)fx0, y0i = (int)fy0;
        const int x0c = min(max(x0i,0),511),   x1c = min(max(x0i+1,0),511);
        const int y0c = min(max(y0i,0),511),   y1c = min(max(y0i+1,0),511);
        uint a00,a01,a10,a11;
        if (useT){
            const uint r0 = (uint)(p*NPLANE + y0c*512);
            const uint r1 = (uint)(p*NPLANE + y1c*512);
            a00 = (r0+x0c)*48u; a01 = (r0+x1c)*48u;
            a10 = (r1+x0c)*48u; a11 = (r1+x1c)*48u;
        } else {
            const uint bp = (uint)p*48u*NPLANE;
            a00 = bp + y0c*512 + x0c; a01 = bp + y0c*512 + x1c;
            a10 = bp + y1c*512 + x0c; a11 = bp + y1c*512 + x1c;
        }
        sA[p][s] = make_uint4(a00,a01,a10,a11);
        // boundary: wx1/wy1 become 0 exactly when the +1 corner is OOB -> matches ref's valid-mask
        sW[p][s] = make_float4(wx0*wy0, wx1*wy0, wx0*wy1, wx1*wy1);
    }

    // ---- phase 2: PE(x,10) -> rows [75..137] ----
    if (tid < 64){
        const int s = tid, g = g0 + s;
        float xn[3];
        xn[0]=x[3*g+0]/3.0f; xn[1]=x[3*g+1]/3.0f; xn[2]=x[3*g+2]/3.0f;
        Hs[s][75]=xn[0]; Hs[s][76]=xn[1]; Hs[s][77]=xn[2];
        float f = 1.0f;
        for (int l=0;l<10;++l){
            #pragma unroll
            for (int m=0;m<3;++m){
                const float a = xn[m]*f;
                Hs[s][78+l*6+m]   = sinf(a);
                Hs[s][78+l*6+3+m] = cosf(a);
            }
            f *= 2.0f;
        }
    } else if (tid < 91){
        // ---- phase 3: PE(d,4) -> rows [48..74], uniform across the block's samples ----
        const int k = tid-64;
        const int ray = g0 >> 7;
        float v;
        if (k < 3) v = d[ray*3+k];
        else {
            const int l=(k-3)/6, r=(k-3)%6;
            const float a = d[ray*3 + (r%3)] * (float)(1<<l);
            v = (r<3)? sinf(a) : cosf(a);
        }
        for (int s2=0;s2<64;++s2) Hs[s2][48+k]=v;
    }
    __syncthreads();

    // ---- phase 4: triplane gather -> rows [0..47] ----
    for (int it = tid; it < 384; it += 256){
        const int s = it & 63;
        const int c0 = (it >> 6)*8;
        float acc[8];
        #pragma unroll
        for (int q=0;q<8;++q) acc[q]=0.f;
        #pragma unroll
        for (int p=0;p<3;++p){
            const uint4  aa = sA[p][s];
            const float4 ww = sW[p][s];
            const uint  av[4] = {aa.x,aa.y,aa.z,aa.w};
            const float wv[4] = {ww.x,ww.y,ww.z,ww.w};
            if (useT){
                #pragma unroll
                for (int cr=0;cr<4;++cr){
                    const uint4 uv = *(const uint4*)(featT + av[cr] + c0);  // 8 bf16, 16B aligned
                    const float w = wv[cr];
                    acc[0]+=w*blo(uv.x); acc[1]+=w*bhi(uv.x);
                    acc[2]+=w*blo(uv.y); acc[3]+=w*bhi(uv.y);
                    acc[4]+=w*blo(uv.z); acc[5]+=w*bhi(uv.z);
                    acc[6]+=w*blo(uv.w); acc[7]+=w*bhi(uv.w);
                }
            } else {
                #pragma unroll
                for (int cr=0;cr<4;++cr){
                    const float w = wv[cr];
                    const float* bsrc = feat + av[cr] + (size_t)c0*NPLANE;
                    #pragma unroll
                    for (int q=0;q<8;++q) acc[q] += w*bsrc[(size_t)q*NPLANE];
                }
            }
        }
        *(float4*)&Hs[s][c0]   = make_float4(acc[0],acc[1],acc[2],acc[3]);
        *(float4*)&Hs[s][c0+4] = make_float4(acc[4],acc[5],acc[6],acc[7]);
    }
    __syncthreads();

    // ---- MLP ----
    mlp_layer<34,2>(Hs, W0, b0, tid);   // K=138
    mlp_layer<32,0>(Hs, W1, b1, tid);   // K=128
    mlp_layer<32,0>(Hs, W2, b2, tid);   // K=128

    // ---- layer 3: 128 -> 4, write out ----
    {
        const int s = tid>>2, j = tid&3;
        float acc = 0.f;
        for (int kk=0; kk<32; ++kk){
            const float4 h = *(const float4*)&Hs[s][kk*4];
            const int k = kk*4;
            acc += h.x*W3[(k+0)*4+j] + h.y*W3[(k+1)*4+j]
                 + h.z*W3[(k+2)*4+j] + h.w*W3[(k+3)*4+j];
        }
        acc += b3[j];
        if (j==3) acc = fmaxf(acc, 0.f);
        out[(size_t)blockIdx.x*256 + tid] = acc;   // (g0+s)*4+j == blk*256+tid, coalesced
    }
}

extern "C" void kernel_launch(void* const* d_in, const int* in_sizes, int n_in,
                              void* d_out, int out_size, void* d_ws, size_t ws_size,
                              hipStream_t stream){
    (void)in_sizes; (void)n_in; (void)out_size;
    const float* x    = (const float*)d_in[0];
    const float* ddir = (const float*)d_in[1];
    const float* feat = (const float*)d_in[2];
    const float* W0 = (const float*)d_in[3];  const float* b0 = (const float*)d_in[4];
    const float* W1 = (const float*)d_in[5];  const float* b1 = (const float*)d_in[6];
    const float* W2 = (const float*)d_in[7];  const float* b2 = (const float*)d_in[8];
    const float* W3 = (const float*)d_in[9];  const float* b3 = (const float*)d_in[10];
    float* out = (float*)d_out;

    const size_t needT = (size_t)3*NPLANE*48*2;   // 75.5 MB bf16 channel-last
    const int useT = (ws_size >= needT) ? 1 : 0;
    unsigned short* featT = (unsigned short*)d_ws;

    if (useT){
        transpose_feat_k<<<3072, 256, 0, stream>>>(feat, featT);
    }
    nerf_fused<<<8192, 256, 0, stream>>>(x, ddir, feat, featT,
                                         W0,b0,W1,b1,W2,b2,W3,b3, out, useT);
}

// Round 5
// 488.570 us; speedup vs baseline: 1.8704x; 1.8704x over previous
//
#include <hip/hip_runtime.h>
#include <hip/hip_bf16.h>
#include <cstdint>
#include <cstddef>

#define NPLANE 262144      // 512*512
#define SBLK 64            // samples per block

typedef unsigned int uint;
typedef __attribute__((ext_vector_type(16))) float f32x16;
typedef __attribute__((ext_vector_type(8))) short short8;

// layout constants (bf16 element units)
#define K0STR 168          // H0 row stride (K padded 138->160); 336B row, 16B-aligned
#define KHSTR 136          // hidden act row stride; 272B row, 16B-aligned
#define W0T_OFF 0          // ushort offsets in d_ws
#define W0T_KW 160
#define W1T_OFF 20480
#define W2T_OFF 36864
#define WS_FEAT_BYTE 131072  // featT at 128KB

__device__ __forceinline__ float blo(uint u){ union{uint i; float f;} v; v.i = u<<16; return v.f; }
__device__ __forceinline__ float bhi(uint u){ union{uint i; float f;} v; v.i = u & 0xffff0000u; return v.f; }
__device__ __forceinline__ unsigned short bf16u(float f){
    __hip_bfloat16 h = __float2bfloat16(f);
    return *reinterpret_cast<unsigned short*>(&h);
}

// ---------------- weight prepass: W[K][N] fp32 -> Wt[N][Kpad] bf16 ----------------
__global__ __launch_bounds__(256) void prep_weights(const float* __restrict__ W0,
                                                    const float* __restrict__ W1,
                                                    const float* __restrict__ W2,
                                                    unsigned short* __restrict__ ws){
    const int idx = blockIdx.x*256 + threadIdx.x;
    if (idx < 20480){                       // W0t [128][160]
        const int n = idx/160, k = idx%160;
        ws[W0T_OFF + idx] = (k < 138) ? bf16u(W0[k*128 + n]) : (unsigned short)0;
    } else if (idx < 36864){                // W1t [128][128]
        const int j = idx - 20480, n = j/128, k = j%128;
        ws[idx] = bf16u(W1[k*128 + n]);
    } else if (idx < 53248){                // W2t [128][128]
        const int j = idx - 36864, n = j/128, k = j%128;
        ws[idx] = bf16u(W2[k*128 + n]);
    }
}

// ---------------- transpose feat (3,48,512,512) fp32 -> (3,512,512,48) bf16 ----------------
__global__ __launch_bounds__(256) void transpose_feat_k(const float* __restrict__ feat,
                                                        unsigned short* __restrict__ featT){
    __shared__ unsigned short lb[256*50];
    const int tid = threadIdx.x;
    const int pos = blockIdx.x*256 + tid;
    const int p  = pos >> 18;
    const int yx = pos & (NPLANE-1);
    const float* src = feat + (size_t)p*48*NPLANE + yx;
    #pragma unroll 4
    for (int c = 0; c < 48; ++c){
        lb[tid*50 + c] = bf16u(src[(size_t)c*NPLANE]);
    }
    __syncthreads();
    uint4* dst = (uint4*)(featT + (size_t)blockIdx.x*(256*48));
    #pragma unroll
    for (int m = 0; m < 6; ++m){
        const int u4 = tid + m*256;
        const int byteoff = u4*16;
        const int smp = byteoff/96;
        const int off = (byteoff%96) >> 2;
        const uint* rw = (const uint*)(lb + smp*50);
        uint4 val; val.x = rw[off]; val.y = rw[off+1]; val.z = rw[off+2]; val.w = rw[off+3];
        dst[u4] = val;
    }
}

// ------- MFMA 32x32x16 MLP layer with RUNTIME-PROBED C/D placement -------
// D1[r] = output row of (reg r, this lane); D2[r] = output col (within 32-tile).
// Correct for ANY self-consistent HW fragment layout (see probe construction below).
template<int KSTEPS, int KW, int SIN, int SOUT>
__device__ __forceinline__ void mfma_layer32(const unsigned short* Hin, unsigned short* Hout,
                                             const unsigned short* __restrict__ Wt,
                                             const float* sB, int tid,
                                             const f32x16 D1, const f32x16 D2){
    const int lane = tid & 63, w = tid >> 6;
    const int ln31 = lane & 31, kg = lane >> 5;     // kg in {0,1}, 8 contig k each
    const int mw = w >> 1;                           // sample-tile: rows mw*32..+32
    const int n0 = (w & 1) * 64;                     // unit-tiles: n0, n0+32
    f32x16 acc0 = (f32x16)0.f, acc1 = (f32x16)0.f;
    #pragma unroll
    for (int ks=0; ks<KSTEPS; ++ks){
        const int kb = ks*16 + kg*8;
        const short8 a   = *reinterpret_cast<const short8*>(Hin + (mw*32+ln31)*SIN + kb);
        const short8 b0v = *reinterpret_cast<const short8*>(Wt + (size_t)(n0+ln31)*KW + kb);
        const short8 b1v = *reinterpret_cast<const short8*>(Wt + (size_t)(n0+32+ln31)*KW + kb);
        acc0 = __builtin_amdgcn_mfma_f32_32x32x16_bf16(a, b0v, acc0, 0,0,0);
        acc1 = __builtin_amdgcn_mfma_f32_32x32x16_bf16(a, b1v, acc1, 0,0,0);
    }
    #pragma unroll
    for (int r=0;r<16;++r){
        const int row = (mw*32 + (int)D1[r]) * SOUT;
        const int c   = (int)D2[r];
        Hout[row + n0 + c]      = bf16u(fmaxf(acc0[r] + sB[n0+c],      0.f));
        Hout[row + n0 + 32 + c] = bf16u(fmaxf(acc1[r] + sB[n0+32+c],   0.f));
    }
    __syncthreads();
}

// ---------------- fused sample + PE + MFMA MLP ----------------
__global__ __launch_bounds__(256) void nerf_mfma(
    const float* __restrict__ x, const float* __restrict__ d,
    const unsigned short* __restrict__ featT,
    const unsigned short* __restrict__ w0t, const unsigned short* __restrict__ w1t,
    const unsigned short* __restrict__ w2t,
    const float* __restrict__ b0, const float* __restrict__ b1, const float* __restrict__ b2,
    const float* __restrict__ W3, const float* __restrict__ b3,
    float* __restrict__ out)
{
    __shared__ unsigned short H0[SBLK*K0STR];   // 21504 B
    __shared__ unsigned short H1[SBLK*KHSTR];   // 17408 B
    __shared__ uint4  sA[3][SBLK];
    __shared__ float4 sWt[3][SBLK];
    __shared__ float  sW3[516];
    __shared__ float  sBias[384];               // b0|b1|b2

    const int tid = threadIdx.x;
    const int g0 = blockIdx.x * SBLK;

    // ---- phase 1: bilinear params; tids 192.. stage sW3 + sBias ----
    if (tid < 192){
        const int s = tid & 63, p = tid >> 6;
        const int g = g0 + s;
        const float xn0 = x[3*g+0]/3.0f, xn1 = x[3*g+1]/3.0f, xn2 = x[3*g+2]/3.0f;
        const float gx = (p==1)? xn1 : xn0;
        const float gy = (p==0)? xn1 : xn2;
        const float ix = ((gx+1.0f)*0.5f)*511.0f;
        const float iy = ((gy+1.0f)*0.5f)*511.0f;
        const float fx0 = floorf(ix), fy0 = floorf(iy);
        const float wx1 = ix - fx0, wy1 = iy - fy0;
        const float wx0 = 1.0f-wx1, wy0 = 1.0f-wy1;
        const int x0i = (int)fx0, y0i = (int)fy0;
        const int x0c = min(max(x0i,0),511),   x1c = min(max(x0i+1,0),511);
        const int y0c = min(max(y0i,0),511),   y1c = min(max(y0i+1,0),511);
        const uint r0 = (uint)(p*NPLANE + y0c*512);
        const uint r1 = (uint)(p*NPLANE + y1c*512);
        sA[p][s] = make_uint4((r0+x0c)*48u, (r0+x1c)*48u, (r1+x0c)*48u, (r1+x1c)*48u);
        sWt[p][s] = make_float4(wx0*wy0, wx1*wy0, wx0*wy1, wx1*wy1);
    } else {
        for (int i = tid-192; i < 516; i += 64)
            sW3[i] = (i < 512) ? W3[i] : b3[i-512];
        for (int i = tid-192; i < 384; i += 64)
            sBias[i] = (i < 128) ? b0[i] : (i < 256) ? b1[i-128] : b2[i-256];
    }

    // ---- phase 2: PE(x,10) -> cols [75..137], zero-pad [138..159] ----
    if (tid < 64){
        const int s = tid, g = g0 + s;
        float xn[3];
        xn[0]=x[3*g+0]/3.0f; xn[1]=x[3*g+1]/3.0f; xn[2]=x[3*g+2]/3.0f;
        unsigned short* row = H0 + s*K0STR;
        row[75]=bf16u(xn[0]); row[76]=bf16u(xn[1]); row[77]=bf16u(xn[2]);
        float f = 1.0f;
        for (int l=0;l<10;++l){
            #pragma unroll
            for (int m=0;m<3;++m){
                const float a = xn[m]*f;
                row[78+l*6+m]   = bf16u(sinf(a));
                row[78+l*6+3+m] = bf16u(cosf(a));
            }
            f *= 2.0f;
        }
        #pragma unroll
        for (int k=138;k<160;++k) row[k] = 0;
    } else if (tid < 91){
        // ---- phase 3: PE(d,4) -> cols [48..74], uniform across block ----
        const int k = tid-64;
        const int ray = g0 >> 7;
        float v;
        if (k < 3) v = d[ray*3+k];
        else {
            const int l=(k-3)/6, r=(k-3)%6;
            const float a = d[ray*3 + (r%3)] * (float)(1<<l);
            v = (r<3)? sinf(a) : cosf(a);
        }
        const unsigned short bv = bf16u(v);
        for (int s2=0;s2<64;++s2) H0[s2*K0STR + 48 + k] = bv;
    }
    __syncthreads();

    // ---- phase 4: triplane gather -> cols [0..47] ----
    for (int it = tid; it < 384; it += 256){
        const int s = it & 63;
        const int c0 = (it >> 6)*8;
        float acc[8];
        #pragma unroll
        for (int q=0;q<8;++q) acc[q]=0.f;
        #pragma unroll
        for (int p=0;p<3;++p){
            const uint4  aa = sA[p][s];
            const float4 ww = sWt[p][s];
            const uint  av[4] = {aa.x,aa.y,aa.z,aa.w};
            const float wv[4] = {ww.x,ww.y,ww.z,ww.w};
            #pragma unroll
            for (int cr=0;cr<4;++cr){
                const uint4 uv = *(const uint4*)(featT + av[cr] + c0);
                const float w = wv[cr];
                acc[0]+=w*blo(uv.x); acc[1]+=w*bhi(uv.x);
                acc[2]+=w*blo(uv.y); acc[3]+=w*bhi(uv.y);
                acc[4]+=w*blo(uv.z); acc[5]+=w*bhi(uv.z);
                acc[6]+=w*blo(uv.w); acc[7]+=w*bhi(uv.w);
            }
        }
        union { unsigned short us[8]; uint4 v; } pk;
        #pragma unroll
        for (int q=0;q<8;++q) pk.us[q] = bf16u(acc[q]);
        *(uint4*)(H0 + s*K0STR + c0) = pk.v;
    }

    // ---- layout probes (before barrier; uses only registers) ----
    // A-probe has its only nonzero at (kg==0, elem 0) -> hardware k* column;
    // B-probe likewise at the same (kg==0, elem 0) -> same k* row. Then
    // D1[r][c] = row_index, D2[r][c] = col_index, for whatever (reg,lane)->(row,col)
    // map the silicon uses. Stores below use these probed indices.
    const int lane = tid & 63, ln31 = lane & 31, kg = lane >> 5;
    short8 pa = {0,0,0,0,0,0,0,0}, pb = pa, qa = pa, qb = pa;
    if (kg == 0){
        pa[0] = (short)bf16u((float)ln31);   // A[ln31][k*] = ln31
        pb[0] = (short)bf16u(1.0f);          // B[k*][ln31] = 1
        qa[0] = (short)bf16u(1.0f);          // A[ln31][k*] = 1
        qb[0] = (short)bf16u((float)ln31);   // B[k*][ln31] = ln31
    }
    const f32x16 zz = (f32x16)0.f;
    const f32x16 D1 = __builtin_amdgcn_mfma_f32_32x32x16_bf16(pa, pb, zz, 0,0,0);
    const f32x16 D2 = __builtin_amdgcn_mfma_f32_32x32x16_bf16(qa, qb, zz, 0,0,0);
    __syncthreads();

    // ---- MFMA MLP: L0 H0->H1, L1 H1->H0, L2 H0->H1 ----
    mfma_layer32<10, W0T_KW, K0STR, KHSTR>(H0, H1, w0t, sBias,       tid, D1, D2);
    mfma_layer32<8,  128,    KHSTR, KHSTR>(H1, H0, w1t, sBias + 128, tid, D1, D2);
    mfma_layer32<8,  128,    KHSTR, KHSTR>(H0, H1, w2t, sBias + 256, tid, D1, D2);

    // ---- final layer 128->4 (fp32 weights from LDS) ----
    {
        const int s = tid>>2, j = tid&3;
        const unsigned short* hrow = H1 + s*KHSTR;
        float acc = 0.f;
        #pragma unroll
        for (int q=0;q<16;++q){
            const uint4 u = *(const uint4*)(hrow + q*8);
            const int k = q*8;
            acc += blo(u.x)*sW3[(k+0)*4+j] + bhi(u.x)*sW3[(k+1)*4+j]
                 + blo(u.y)*sW3[(k+2)*4+j] + bhi(u.y)*sW3[(k+3)*4+j]
                 + blo(u.z)*sW3[(k+4)*4+j] + bhi(u.z)*sW3[(k+5)*4+j]
                 + blo(u.w)*sW3[(k+6)*4+j] + bhi(u.w)*sW3[(k+7)*4+j];
        }
        acc += sW3[512+j];
        if (j==3) acc = fmaxf(acc, 0.f);
        out[(size_t)blockIdx.x*256 + tid] = acc;
    }
}

// ================= fallback (round-2 kernel, channel-major gather, fp32 MLP) =================
#define STR 148
template<int K4, int KTAIL>
__device__ __forceinline__ void mlp_layer_fb(float (*Hs)[STR], const float* __restrict__ W,
                                             const float* __restrict__ B, int tid){
    const int tx = tid & 31, ty = tid >> 5;
    const int s0 = ty*8, j0 = tx*4;
    float acc[8][4];
    #pragma unroll
    for (int i=0;i<8;++i){ acc[i][0]=0.f; acc[i][1]=0.f; acc[i][2]=0.f; acc[i][3]=0.f; }
    for (int kk = 0; kk < K4; ++kk){
        const int k = kk*4;
        const float4 wa = *(const float4*)(W + (size_t)(k+0)*128 + j0);
        const float4 wb = *(const float4*)(W + (size_t)(k+1)*128 + j0);
        const float4 wc = *(const float4*)(W + (size_t)(k+2)*128 + j0);
        const float4 wd = *(const float4*)(W + (size_t)(k+3)*128 + j0);
        #pragma unroll
        for (int i=0;i<8;++i){
            const float4 h = *(const float4*)&Hs[s0+i][k];
            acc[i][0] += h.x*wa.x + h.y*wb.x + h.z*wc.x + h.w*wd.x;
            acc[i][1] += h.x*wa.y + h.y*wb.y + h.z*wc.y + h.w*wd.y;
            acc[i][2] += h.x*wa.z + h.y*wb.z + h.z*wc.z + h.w*wd.z;
            acc[i][3] += h.x*wa.w + h.y*wb.w + h.z*wc.w + h.w*wd.w;
        }
    }
    #pragma unroll
    for (int t=0;t<KTAIL;++t){
        const int k = K4*4+t;
        const float4 wa = *(const float4*)(W + (size_t)k*128 + j0);
        #pragma unroll
        for (int i=0;i<8;++i){
            const float h = Hs[s0+i][k];
            acc[i][0] += h*wa.x; acc[i][1] += h*wa.y; acc[i][2] += h*wa.z; acc[i][3] += h*wa.w;
        }
    }
    const float4 bb = *(const float4*)(B + j0);
    __syncthreads();
    #pragma unroll
    for (int i=0;i<8;++i){
        float4 o;
        o.x = fmaxf(acc[i][0]+bb.x, 0.f);
        o.y = fmaxf(acc[i][1]+bb.y, 0.f);
        o.z = fmaxf(acc[i][2]+bb.z, 0.f);
        o.w = fmaxf(acc[i][3]+bb.w, 0.f);
        *(float4*)&Hs[s0+i][j0] = o;
    }
    __syncthreads();
}

__global__ __launch_bounds__(256) void nerf_fused_fb(
    const float* __restrict__ x, const float* __restrict__ d,
    const float* __restrict__ feat,
    const float* __restrict__ W0, const float* __restrict__ b0,
    const float* __restrict__ W1, const float* __restrict__ b1,
    const float* __restrict__ W2, const float* __restrict__ b2,
    const float* __restrict__ W3, const float* __restrict__ b3,
    float* __restrict__ out)
{
    __shared__ float Hs[SBLK][STR];
    __shared__ uint4  sA[3][SBLK];
    __shared__ float4 sW[3][SBLK];

    const int tid = threadIdx.x;
    const int g0 = blockIdx.x * SBLK;

    if (tid < 192){
        const int s = tid & 63, p = tid >> 6;
        const int g = g0 + s;
        const float xn0 = x[3*g+0]/3.0f, xn1 = x[3*g+1]/3.0f, xn2 = x[3*g+2]/3.0f;
        const float gx = (p==1)? xn1 : xn0;
        const float gy = (p==0)? xn1 : xn2;
        const float ix = ((gx+1.0f)*0.5f)*511.0f;
        const float iy = ((gy+1.0f)*0.5f)*511.0f;
        const float fx0 = floorf(ix), fy0 = floorf(iy);
        const float wx1 = ix - fx0, wy1 = iy - fy0;
        const float wx0 = 1.0f-wx1, wy0 = 1.0f-wy1;
        const int x0i = (int)fx0, y0i = (int)fy0;
        const int x0c = min(max(x0i,0),511),   x1c = min(max(x0i+1,0),511);
        const int y0c = min(max(y0i,0),511),   y1c = min(max(y0i+1,0),511);
        const uint bp = (uint)p*48u*NPLANE;
        sA[p][s] = make_uint4(bp + y0c*512 + x0c, bp + y0c*512 + x1c,
                              bp + y1c*512 + x0c, bp + y1c*512 + x1c);
        sW[p][s] = make_float4(wx0*wy0, wx1*wy0, wx0*wy1, wx1*wy1);
    }
    if (tid < 64){
        const int s = tid, g = g0 + s;
        float xn[3];
        xn[0]=x[3*g+0]/3.0f; xn[1]=x[3*g+1]/3.0f; xn[2]=x[3*g+2]/3.0f;
        Hs[s][75]=xn[0]; Hs[s][76]=xn[1]; Hs[s][77]=xn[2];
        float f = 1.0f;
        for (int l=0;l<10;++l){
            #pragma unroll
            for (int m=0;m<3;++m){
                const float a = xn[m]*f;
                Hs[s][78+l*6+m]   = sinf(a);
                Hs[s][78+l*6+3+m] = cosf(a);
            }
            f *= 2.0f;
        }
    } else if (tid < 91){
        const int k = tid-64;
        const int ray = g0 >> 7;
        float v;
        if (k < 3) v = d[ray*3+k];
        else {
            const int l=(k-3)/6, r=(k-3)%6;
            const float a = d[ray*3 + (r%3)] * (float)(1<<l);
            v = (r<3)? sinf(a) : cosf(a);
        }
        for (int s2=0;s2<64;++s2) Hs[s2][48+k]=v;
    }
    __syncthreads();

    for (int it = tid; it < 384; it += 256){
        const int s = it & 63;
        const int c0 = (it >> 6)*8;
        float acc[8];
        #pragma unroll
        for (int q=0;q<8;++q) acc[q]=0.f;
        #pragma unroll
        for (int p=0;p<3;++p){
            const uint4  aa = sA[p][s];
            const float4 ww = sW[p][s];
            const uint  av[4] = {aa.x,aa.y,aa.z,aa.w};
            const float wv[4] = {ww.x,ww.y,ww.z,ww.w};
            #pragma unroll
            for (int cr=0;cr<4;++cr){
                const float w = wv[cr];
                const float* bsrc = feat + av[cr] + (size_t)c0*NPLANE;
                #pragma unroll
                for (int q=0;q<8;++q) acc[q] += w*bsrc[(size_t)q*NPLANE];
            }
        }
        *(float4*)&Hs[s][c0]   = make_float4(acc[0],acc[1],acc[2],acc[3]);
        *(float4*)&Hs[s][c0+4] = make_float4(acc[4],acc[5],acc[6],acc[7]);
    }
    __syncthreads();

    mlp_layer_fb<34,2>(Hs, W0, b0, tid);
    mlp_layer_fb<32,0>(Hs, W1, b1, tid);
    mlp_layer_fb<32,0>(Hs, W2, b2, tid);

    {
        const int s = tid>>2, j = tid&3;
        float acc = 0.f;
        for (int kk=0; kk<32; ++kk){
            const float4 h = *(const float4*)&Hs[s][kk*4];
            const int k = kk*4;
            acc += h.x*W3[(k+0)*4+j] + h.y*W3[(k+1)*4+j]
                 + h.z*W3[(k+2)*4+j] + h.w*W3[(k+3)*4+j];
        }
        acc += b3[j];
        if (j==3) acc = fmaxf(acc, 0.f);
        out[(size_t)blockIdx.x*256 + tid] = acc;
    }
}

extern "C" void kernel_launch(void* const* d_in, const int* in_sizes, int n_in,
                              void* d_out, int out_size, void* d_ws, size_t ws_size,
                              hipStream_t stream){
    (void)in_sizes; (void)n_in; (void)out_size;
    const float* x    = (const float*)d_in[0];
    const float* ddir = (const float*)d_in[1];
    const float* feat = (const float*)d_in[2];
    const float* W0 = (const float*)d_in[3];  const float* b0 = (const float*)d_in[4];
    const float* W1 = (const float*)d_in[5];  const float* b1 = (const float*)d_in[6];
    const float* W2 = (const float*)d_in[7];  const float* b2 = (const float*)d_in[8];
    const float* W3 = (const float*)d_in[9];  const float* b3 = (const float*)d_in[10];
    float* out = (float*)d_out;

    const size_t needAll = (size_t)WS_FEAT_BYTE + (size_t)3*NPLANE*48*2;
    if (ws_size >= needAll){
        unsigned short* wsu  = (unsigned short*)d_ws;
        unsigned short* featT = (unsigned short*)((char*)d_ws + WS_FEAT_BYTE);
        prep_weights<<<208, 256, 0, stream>>>(W0, W1, W2, wsu);
        transpose_feat_k<<<3072, 256, 0, stream>>>(feat, featT);
        nerf_mfma<<<8192, 256, 0, stream>>>(x, ddir, featT,
                                            wsu + W0T_OFF, wsu + W1T_OFF, wsu + W2T_OFF,
                                            b0, b1, b2, W3, b3, out);
    } else {
        nerf_fused_fb<<<8192, 256, 0, stream>>>(x, ddir, feat,
                                                W0,b0,W1,b1,W2,b2,W3,b3, out);
    }
}

// Round 6
// 351.673 us; speedup vs baseline: 2.5984x; 1.3893x over previous
//
#include <hip/hip_runtime.h>
#include <hip/hip_bf16.h>
#include <cstdint>
#include <cstddef>

#define NPLANE 262144      // 512*512
#define K0STR 168          // H row stride (bf16): 336B, words%32=20 -> gcd4 bank spread
#define W0T_KW 160
#define W1T_OFF 20480
#define W2T_OFF 36864
#define WS_FEAT_BYTE 131072

typedef unsigned int uint;
typedef __attribute__((ext_vector_type(16))) float f32x16;
typedef __attribute__((ext_vector_type(8))) short short8;

__device__ __forceinline__ float blo(uint u){ union{uint i; float f;} v; v.i = u<<16; return v.f; }
__device__ __forceinline__ float bhi(uint u){ union{uint i; float f;} v; v.i = u & 0xffff0000u; return v.f; }
__device__ __forceinline__ unsigned short bf16u(float f){
    __hip_bfloat16 h = __float2bfloat16(f);
    return *reinterpret_cast<unsigned short*>(&h);
}

// ---------------- weight prepass: W[K][N] fp32 -> Wt[N][Kpad] bf16 ----------------
__global__ __launch_bounds__(256) void prep_weights(const float* __restrict__ W0,
                                                    const float* __restrict__ W1,
                                                    const float* __restrict__ W2,
                                                    unsigned short* __restrict__ ws){
    const int idx = blockIdx.x*256 + threadIdx.x;
    if (idx < 20480){                       // W0t [128][160]
        const int n = idx/160, k = idx%160;
        ws[idx] = (k < 138) ? bf16u(W0[k*128 + n]) : (unsigned short)0;
    } else if (idx < 36864){                // W1t [128][128]
        const int j = idx - 20480, n = j/128, k = j%128;
        ws[idx] = bf16u(W1[k*128 + n]);
    } else if (idx < 53248){                // W2t [128][128]
        const int j = idx - 36864, n = j/128, k = j%128;
        ws[idx] = bf16u(W2[k*128 + n]);
    }
}

// ---------------- transpose feat (3,48,512,512) fp32 -> (3,512,512,48) bf16 ----------------
__global__ __launch_bounds__(256) void transpose_feat_k(const float* __restrict__ feat,
                                                        unsigned short* __restrict__ featT){
    __shared__ unsigned short lb[256*50];
    const int tid = threadIdx.x;
    const int pos = blockIdx.x*256 + tid;
    const int p  = pos >> 18;
    const int yx = pos & (NPLANE-1);
    const float* src = feat + (size_t)p*48*NPLANE + yx;
    #pragma unroll 4
    for (int c = 0; c < 48; ++c){
        lb[tid*50 + c] = bf16u(src[(size_t)c*NPLANE]);
    }
    __syncthreads();
    uint4* dst = (uint4*)(featT + (size_t)blockIdx.x*(256*48));
    #pragma unroll
    for (int m = 0; m < 6; ++m){
        const int u4 = tid + m*256;
        const int byteoff = u4*16;
        const int smp = byteoff/96;
        const int off = (byteoff%96) >> 2;
        const uint* rw = (const uint*)(lb + smp*50);
        uint4 val; val.x = rw[off]; val.y = rw[off+1]; val.z = rw[off+2]; val.w = rw[off+3];
        dst[u4] = val;
    }
}

// ---- wave-local MFMA layer (in-place on this wave's 32 rows of H) ----
// probe-derived placement pr[r] = (row<<8)|col, correct for any HW fragment layout
template<int KSTEPS, int KW>
__device__ __forceinline__ void layer_w(unsigned short* Hw, const unsigned short* __restrict__ Wt,
                                        const float* sB, int ln31, int kg, const int* pr){
    f32x16 acc[4];
    #pragma unroll
    for (int nt=0;nt<4;++nt) acc[nt] = (f32x16)0.f;
    #pragma unroll
    for (int ks=0; ks<KSTEPS; ++ks){
        const int kb = ks*16 + kg*8;
        const short8 a = *reinterpret_cast<const short8*>(Hw + ln31*K0STR + kb);
        #pragma unroll
        for (int nt=0;nt<4;++nt){
            const short8 b = *reinterpret_cast<const short8*>(Wt + (size_t)(nt*32+ln31)*KW + kb);
            acc[nt] = __builtin_amdgcn_mfma_f32_32x32x16_bf16(a, b, acc[nt], 0,0,0);
        }
    }
    #pragma unroll
    for (int nt=0;nt<4;++nt){
        #pragma unroll
        for (int r=0;r<16;++r){
            const int row = pr[r] >> 8;
            const int col = nt*32 + (pr[r] & 255);
            Hw[row*K0STR + col] = bf16u(fmaxf(acc[nt][r] + sB[col], 0.f));
        }
    }
}

// ---------------- fused kernel: 2 autonomous waves x 32 samples, zero barriers ----------------
__global__ __launch_bounds__(128) void nerf_mfma(
    const float* __restrict__ x, const float* __restrict__ d,
    const unsigned short* __restrict__ featT,
    const unsigned short* __restrict__ w0t, const unsigned short* __restrict__ w1t,
    const unsigned short* __restrict__ w2t,
    const float* __restrict__ b0, const float* __restrict__ b1, const float* __restrict__ b2,
    const float* __restrict__ W3, const float* __restrict__ b3,
    float* __restrict__ out)
{
    __shared__ unsigned short H[64*K0STR];   // 21504 B, wave w owns rows [w*32, w*32+32)
    __shared__ uint4  sA[3][64];
    __shared__ float4 sWt[3][64];
    __shared__ float  sBias[384];            // b0|b1|b2 (each wave duplicate-writes)
    __shared__ float  sW3[516];              // W3 + b3

    const int tid  = threadIdx.x;
    const int wid  = tid >> 6, lane = tid & 63;
    const int ln31 = lane & 31, kg = lane >> 5;
    const int g0   = blockIdx.x * 64;
    const int sbase = wid * 32;              // this wave's local sample base
    unsigned short* Hw = H + sbase*K0STR;

    // ---- layout probes (register-only, verbatim from round 5) ----
    short8 pa = {0,0,0,0,0,0,0,0}, pb = pa, qa = pa, qb = pa;
    if (kg == 0){
        pa[0] = (short)bf16u((float)ln31);
        pb[0] = (short)bf16u(1.0f);
        qa[0] = (short)bf16u(1.0f);
        qb[0] = (short)bf16u((float)ln31);
    }
    const f32x16 zz = (f32x16)0.f;
    const f32x16 D1 = __builtin_amdgcn_mfma_f32_32x32x16_bf16(pa, pb, zz, 0,0,0);
    const f32x16 D2 = __builtin_amdgcn_mfma_f32_32x32x16_bf16(qa, qb, zz, 0,0,0);
    int pr[16];
    #pragma unroll
    for (int r=0;r<16;++r) pr[r] = (((int)D1[r]) << 8) | (int)D2[r];

    // ---- stage biases + W3 (both waves write identical values: benign) ----
    for (int i = lane; i < 516; i += 64) sW3[i] = (i < 512) ? W3[i] : b3[i-512];
    for (int i = lane; i < 384; i += 64)
        sBias[i] = (i < 128) ? b0[i] : (i < 256) ? b1[i-128] : b2[i-256];

    // ---- bilinear params for this wave's 32 samples (units: (s32,p)) ----
    #pragma unroll
    for (int rr=0; rr<2; ++rr){
        int s32, p;
        if (rr == 0){ s32 = ln31; p = kg; }
        else { if (lane >= 32) break; s32 = lane; p = 2; }
        const int g = g0 + sbase + s32;
        const float xn0 = x[3*g+0]*(1.0f/3.0f), xn1 = x[3*g+1]*(1.0f/3.0f), xn2 = x[3*g+2]*(1.0f/3.0f);
        const float gx = (p==1)? xn1 : xn0;
        const float gy = (p==0)? xn1 : xn2;
        const float ix = ((gx+1.0f)*0.5f)*511.0f;
        const float iy = ((gy+1.0f)*0.5f)*511.0f;
        const float fx0 = floorf(ix), fy0 = floorf(iy);
        const float wx1 = ix - fx0, wy1 = iy - fy0;
        const float wx0 = 1.0f-wx1, wy0 = 1.0f-wy1;
        const int x0i = (int)fx0, y0i = (int)fy0;
        const int x0c = min(max(x0i,0),511),   x1c = min(max(x0i+1,0),511);
        const int y0c = min(max(y0i,0),511),   y1c = min(max(y0i+1,0),511);
        const uint r0 = (uint)(p*NPLANE + y0c*512);
        const uint r1 = (uint)(p*NPLANE + y1c*512);
        sA[p][sbase+s32]  = make_uint4((r0+x0c)*48u, (r0+x1c)*48u, (r1+x0c)*48u, (r1+x1c)*48u);
        sWt[p][sbase+s32] = make_float4(wx0*wy0, wx1*wy0, wx0*wy1, wx1*wy1);
    }

    // ---- PE(x,10) spread across all lanes: round0 (s32,m=0/1), round1 lanes<32 m=2 ----
    #pragma unroll
    for (int rr=0; rr<2; ++rr){
        int s32, m;
        if (rr == 0){ s32 = ln31; m = kg; }
        else {
            if (lane >= 32){
                // ---- PE(d,4): ray-uniform, computed by idle lanes ----
                const int k = lane - 32;
                if (k < 27){
                    const int ray = g0 >> 7;
                    float v;
                    if (k < 3) v = d[ray*3+k];
                    else {
                        const int l=(k-3)/6, r=(k-3)%6;
                        const float a = d[ray*3 + (r%3)] * (float)(1<<l);
                        v = (r<3)? sinf(a) : cosf(a);
                    }
                    const unsigned short bv = bf16u(v);
                    for (int s2=0;s2<32;++s2) H[(sbase+s2)*K0STR + 48 + k] = bv;
                }
                break;
            }
            s32 = lane; m = 2;
        }
        const int g = g0 + sbase + s32;
        const float xn = x[3*g+m]*(1.0f/3.0f);
        unsigned short* row = H + (sbase+s32)*K0STR;
        row[75+m] = bf16u(xn);
        float a = xn;
        #pragma unroll
        for (int l=0;l<10;++l){
            float sv, cv;
            sincosf(a, &sv, &cv);
            row[78+l*6+m]   = bf16u(sv);
            row[78+l*6+3+m] = bf16u(cv);
            a *= 2.0f;
        }
    }
    // zero-pad cols 138..143 (K padded to 144)
    if (lane < 32){
        uint* zr = (uint*)(H + (sbase+lane)*K0STR + 138);
        zr[0]=0u; zr[1]=0u; zr[2]=0u;
    }

    // ---- gather: units (s32, chunk) chunk-fastest -> 6 lanes read one 96B corner run ----
    #pragma unroll
    for (int rr=0; rr<3; ++rr){
        const int u = rr*64 + lane;          // 0..191
        const int s32 = u/6, ch = u - s32*6; // s32 0..31, ch 0..5
        const int srow = sbase + s32;
        const int c0 = ch*8;
        float acc[8];
        #pragma unroll
        for (int q=0;q<8;++q) acc[q]=0.f;
        #pragma unroll
        for (int p=0;p<3;++p){
            const uint4  aa = sA[p][srow];
            const float4 ww = sWt[p][srow];
            const uint  av[4] = {aa.x,aa.y,aa.z,aa.w};
            const float wv[4] = {ww.x,ww.y,ww.z,ww.w};
            #pragma unroll
            for (int cr=0;cr<4;++cr){
                const uint4 uv = *(const uint4*)(featT + av[cr] + c0);
                const float w = wv[cr];
                acc[0]+=w*blo(uv.x); acc[1]+=w*bhi(uv.x);
                acc[2]+=w*blo(uv.y); acc[3]+=w*bhi(uv.y);
                acc[4]+=w*blo(uv.z); acc[5]+=w*bhi(uv.z);
                acc[6]+=w*blo(uv.w); acc[7]+=w*bhi(uv.w);
            }
        }
        union { unsigned short us[8]; uint4 v; } pk;
        #pragma unroll
        for (int q=0;q<8;++q) pk.us[q] = bf16u(acc[q]);
        *(uint4*)(H + srow*K0STR + c0) = pk.v;
    }

    // ---- MLP: 3 layers, wave-local, in-place (no barriers anywhere) ----
    layer_w<9, W0T_KW>(Hw, w0t, sBias,       ln31, kg, pr);   // K=144 (138 + zero pad)
    layer_w<8, 128   >(Hw, w1t, sBias + 128, ln31, kg, pr);
    layer_w<8, 128   >(Hw, w2t, sBias + 256, ln31, kg, pr);

    // ---- final layer 128->4 ----
    {
        const int s32 = lane >> 1, jp = (lane & 1)*2;
        const unsigned short* hrow = H + (sbase+s32)*K0STR;
        float a0 = sW3[512+jp], a1 = sW3[513+jp];
        #pragma unroll
        for (int q=0;q<16;++q){
            const uint4 u = *(const uint4*)(hrow + q*8);
            const int k = q*8;
            float h;
            h = blo(u.x); a0 += h*sW3[(k+0)*4+jp]; a1 += h*sW3[(k+0)*4+jp+1];
            h = bhi(u.x); a0 += h*sW3[(k+1)*4+jp]; a1 += h*sW3[(k+1)*4+jp+1];
            h = blo(u.y); a0 += h*sW3[(k+2)*4+jp]; a1 += h*sW3[(k+2)*4+jp+1];
            h = bhi(u.y); a0 += h*sW3[(k+3)*4+jp]; a1 += h*sW3[(k+3)*4+jp+1];
            h = blo(u.z); a0 += h*sW3[(k+4)*4+jp]; a1 += h*sW3[(k+4)*4+jp+1];
            h = bhi(u.z); a0 += h*sW3[(k+5)*4+jp]; a1 += h*sW3[(k+5)*4+jp+1];
            h = blo(u.w); a0 += h*sW3[(k+6)*4+jp]; a1 += h*sW3[(k+6)*4+jp+1];
            h = bhi(u.w); a0 += h*sW3[(k+7)*4+jp]; a1 += h*sW3[(k+7)*4+jp+1];
        }
        if (jp == 2) a1 = fmaxf(a1, 0.f);
        float2 o; o.x = a0; o.y = a1;
        *(float2*)(out + (size_t)(g0+sbase+s32)*4 + jp) = o;
    }
}

// ================= fallback (round-2 kernel, channel-major gather, fp32 MLP) =================
#define STR 148
#define SBLK 64
template<int K4, int KTAIL>
__device__ __forceinline__ void mlp_layer_fb(float (*Hs)[STR], const float* __restrict__ W,
                                             const float* __restrict__ B, int tid){
    const int tx = tid & 31, ty = tid >> 5;
    const int s0 = ty*8, j0 = tx*4;
    float acc[8][4];
    #pragma unroll
    for (int i=0;i<8;++i){ acc[i][0]=0.f; acc[i][1]=0.f; acc[i][2]=0.f; acc[i][3]=0.f; }
    for (int kk = 0; kk < K4; ++kk){
        const int k = kk*4;
        const float4 wa = *(const float4*)(W + (size_t)(k+0)*128 + j0);
        const float4 wb = *(const float4*)(W + (size_t)(k+1)*128 + j0);
        const float4 wc = *(const float4*)(W + (size_t)(k+2)*128 + j0);
        const float4 wd = *(const float4*)(W + (size_t)(k+3)*128 + j0);
        #pragma unroll
        for (int i=0;i<8;++i){
            const float4 h = *(const float4*)&Hs[s0+i][k];
            acc[i][0] += h.x*wa.x + h.y*wb.x + h.z*wc.x + h.w*wd.x;
            acc[i][1] += h.x*wa.y + h.y*wb.y + h.z*wc.y + h.w*wd.y;
            acc[i][2] += h.x*wa.z + h.y*wb.z + h.z*wc.z + h.w*wd.z;
            acc[i][3] += h.x*wa.w + h.y*wb.w + h.z*wc.w + h.w*wd.w;
        }
    }
    #pragma unroll
    for (int t=0;t<KTAIL;++t){
        const int k = K4*4+t;
        const float4 wa = *(const float4*)(W + (size_t)k*128 + j0);
        #pragma unroll
        for (int i=0;i<8;++i){
            const float h = Hs[s0+i][k];
            acc[i][0] += h*wa.x; acc[i][1] += h*wa.y; acc[i][2] += h*wa.z; acc[i][3] += h*wa.w;
        }
    }
    const float4 bb = *(const float4*)(B + j0);
    __syncthreads();
    #pragma unroll
    for (int i=0;i<8;++i){
        float4 o;
        o.x = fmaxf(acc[i][0]+bb.x, 0.f);
        o.y = fmaxf(acc[i][1]+bb.y, 0.f);
        o.z = fmaxf(acc[i][2]+bb.z, 0.f);
        o.w = fmaxf(acc[i][3]+bb.w, 0.f);
        *(float4*)&Hs[s0+i][j0] = o;
    }
    __syncthreads();
}

__global__ __launch_bounds__(256) void nerf_fused_fb(
    const float* __restrict__ x, const float* __restrict__ d,
    const float* __restrict__ feat,
    const float* __restrict__ W0, const float* __restrict__ b0,
    const float* __restrict__ W1, const float* __restrict__ b1,
    const float* __restrict__ W2, const float* __restrict__ b2,
    const float* __restrict__ W3, const float* __restrict__ b3,
    float* __restrict__ out)
{
    __shared__ float Hs[SBLK][STR];
    __shared__ uint4  sA[3][SBLK];
    __shared__ float4 sW[3][SBLK];

    const int tid = threadIdx.x;
    const int g0 = blockIdx.x * SBLK;

    if (tid < 192){
        const int s = tid & 63, p = tid >> 6;
        const int g = g0 + s;
        const float xn0 = x[3*g+0]/3.0f, xn1 = x[3*g+1]/3.0f, xn2 = x[3*g+2]/3.0f;
        const float gx = (p==1)? xn1 : xn0;
        const float gy = (p==0)? xn1 : xn2;
        const float ix = ((gx+1.0f)*0.5f)*511.0f;
        const float iy = ((gy+1.0f)*0.5f)*511.0f;
        const float fx0 = floorf(ix), fy0 = floorf(iy);
        const float wx1 = ix - fx0, wy1 = iy - fy0;
        const float wx0 = 1.0f-wx1, wy0 = 1.0f-wy1;
        const int x0i = (int)fx0, y0i = (int)fy0;
        const int x0c = min(max(x0i,0),511),   x1c = min(max(x0i+1,0),511);
        const int y0c = min(max(y0i,0),511),   y1c = min(max(y0i+1,0),511);
        const uint bp = (uint)p*48u*NPLANE;
        sA[p][s] = make_uint4(bp + y0c*512 + x0c, bp + y0c*512 + x1c,
                              bp + y1c*512 + x0c, bp + y1c*512 + x1c);
        sW[p][s] = make_float4(wx0*wy0, wx1*wy0, wx0*wy1, wx1*wy1);
    }
    if (tid < 64){
        const int s = tid, g = g0 + s;
        float xn[3];
        xn[0]=x[3*g+0]/3.0f; xn[1]=x[3*g+1]/3.0f; xn[2]=x[3*g+2]/3.0f;
        Hs[s][75]=xn[0]; Hs[s][76]=xn[1]; Hs[s][77]=xn[2];
        float f = 1.0f;
        for (int l=0;l<10;++l){
            #pragma unroll
            for (int m=0;m<3;++m){
                const float a = xn[m]*f;
                Hs[s][78+l*6+m]   = sinf(a);
                Hs[s][78+l*6+3+m] = cosf(a);
            }
            f *= 2.0f;
        }
    } else if (tid < 91){
        const int k = tid-64;
        const int ray = g0 >> 7;
        float v;
        if (k < 3) v = d[ray*3+k];
        else {
            const int l=(k-3)/6, r=(k-3)%6;
            const float a = d[ray*3 + (r%3)] * (float)(1<<l);
            v = (r<3)? sinf(a) : cosf(a);
        }
        for (int s2=0;s2<64;++s2) Hs[s2][48+k]=v;
    }
    __syncthreads();

    for (int it = tid; it < 384; it += 256){
        const int s = it & 63;
        const int c0 = (it >> 6)*8;
        float acc[8];
        #pragma unroll
        for (int q=0;q<8;++q) acc[q]=0.f;
        #pragma unroll
        for (int p=0;p<3;++p){
            const uint4  aa = sA[p][s];
            const float4 ww = sW[p][s];
            const uint  av[4] = {aa.x,aa.y,aa.z,aa.w};
            const float wv[4] = {ww.x,ww.y,ww.z,ww.w};
            #pragma unroll
            for (int cr=0;cr<4;++cr){
                const float w = wv[cr];
                const float* bsrc = feat + av[cr] + (size_t)c0*NPLANE;
                #pragma unroll
                for (int q=0;q<8;++q) acc[q] += w*bsrc[(size_t)q*NPLANE];
            }
        }
        *(float4*)&Hs[s][c0]   = make_float4(acc[0],acc[1],acc[2],acc[3]);
        *(float4*)&Hs[s][c0+4] = make_float4(acc[4],acc[5],acc[6],acc[7]);
    }
    __syncthreads();

    mlp_layer_fb<34,2>(Hs, W0, b0, tid);
    mlp_layer_fb<32,0>(Hs, W1, b1, tid);
    mlp_layer_fb<32,0>(Hs, W2, b2, tid);

    {
        const int s = tid>>2, j = tid&3;
        float acc = 0.f;
        for (int kk=0; kk<32; ++kk){
            const float4 h = *(const float4*)&Hs[s][kk*4];
            const int k = kk*4;
            acc += h.x*W3[(k+0)*4+j] + h.y*W3[(k+1)*4+j]
                 + h.z*W3[(k+2)*4+j] + h.w*W3[(k+3)*4+j];
        }
        acc += b3[j];
        if (j==3) acc = fmaxf(acc, 0.f);
        out[(size_t)blockIdx.x*256 + tid] = acc;
    }
}

extern "C" void kernel_launch(void* const* d_in, const int* in_sizes, int n_in,
                              void* d_out, int out_size, void* d_ws, size_t ws_size,
                              hipStream_t stream){
    (void)in_sizes; (void)n_in; (void)out_size;
    const float* x    = (const float*)d_in[0];
    const float* ddir = (const float*)d_in[1];
    const float* feat = (const float*)d_in[2];
    const float* W0 = (const float*)d_in[3];  const float* b0 = (const float*)d_in[4];
    const float* W1 = (const float*)d_in[5];  const float* b1 = (const float*)d_in[6];
    const float* W2 = (const float*)d_in[7];  const float* b2 = (const float*)d_in[8];
    const float* W3 = (const float*)d_in[9];  const float* b3 = (const float*)d_in[10];
    float* out = (float*)d_out;

    const size_t needAll = (size_t)WS_FEAT_BYTE + (size_t)3*NPLANE*48*2;
    if (ws_size >= needAll){
        unsigned short* wsu   = (unsigned short*)d_ws;
        unsigned short* featT = (unsigned short*)((char*)d_ws + WS_FEAT_BYTE);
        prep_weights<<<208, 256, 0, stream>>>(W0, W1, W2, wsu);
        transpose_feat_k<<<3072, 256, 0, stream>>>(feat, featT);
        nerf_mfma<<<8192, 128, 0, stream>>>(x, ddir, featT,
                                            wsu, wsu + W1T_OFF, wsu + W2T_OFF,
                                            b0, b1, b2, W3, b3, out);
    } else {
        nerf_fused_fb<<<8192, 256, 0, stream>>>(x, ddir, feat,
                                                W0,b0,W1,b1,W2,b2,W3,b3, out);
    }
}

// Round 7
// 305.976 us; speedup vs baseline: 2.9865x; 1.1494x over previous
//
#include <hip/hip_runtime.h>
#include <hip/hip_bf16.h>
#include <cstdint>
#include <cstddef>

#define NPLANE 262144      // 512*512
#define K0STR 168          // H row stride (bf16): 336B/row, 16B aligned
#define WS_FEAT_BYTE 131072
// packed-weight offsets (shorts): L0 9 ksteps, L1/L2 8
#define P0_OFF 0
#define P1_OFF 18432
#define P2_OFF 34816

typedef unsigned int uint;
typedef __attribute__((ext_vector_type(16))) float f32x16;
typedef __attribute__((ext_vector_type(8))) short short8;

__device__ __forceinline__ float blo(uint u){ union{uint i; float f;} v; v.i = u<<16; return v.f; }
__device__ __forceinline__ float bhi(uint u){ union{uint i; float f;} v; v.i = u & 0xffff0000u; return v.f; }
__device__ __forceinline__ unsigned short bf16u(float f){
    __hip_bfloat16 h = __float2bfloat16(f);
    return *reinterpret_cast<unsigned short*>(&h);
}

// -------- weight prepass: W[K][N] fp32 -> MFMA-fragment-packed bf16 --------
// packed index = ((ks*4+nt)*64 + lane)*8 + e ; lane=kg*32+ln31
// value = W[ks*16 + kg*8 + e][nt*32 + ln31]  (zero-padded past K)
__global__ __launch_bounds__(256) void prep_weights(const float* __restrict__ W0,
                                                    const float* __restrict__ W1,
                                                    const float* __restrict__ W2,
                                                    unsigned short* __restrict__ ws){
    const int idx = blockIdx.x*256 + threadIdx.x;
    if (idx >= 51200) return;
    const float* W; int base, K;
    if (idx < P1_OFF){ W = W0; base = idx - P0_OFF; K = 138; }
    else if (idx < P2_OFF){ W = W1; base = idx - P1_OFF; K = 128; }
    else { W = W2; base = idx - P2_OFF; K = 128; }
    const int e  = base & 7;
    const int l  = (base >> 3) & 63;
    const int fr = base >> 9;
    const int ks = fr >> 2, nt = fr & 3;
    const int k  = ks*16 + (l >> 5)*8 + e;
    const int n  = nt*32 + (l & 31);
    ws[idx] = (k < K) ? bf16u(W[k*128 + n]) : (unsigned short)0;
}

// ---------------- transpose feat (3,48,512,512) fp32 -> (3,512,512,48) bf16 ----------------
__global__ __launch_bounds__(256) void transpose_feat_k(const float* __restrict__ feat,
                                                        unsigned short* __restrict__ featT){
    __shared__ unsigned short lb[256*50];
    const int tid = threadIdx.x;
    const int pos = blockIdx.x*256 + tid;
    const int p  = pos >> 18;
    const int yx = pos & (NPLANE-1);
    const float* src = feat + (size_t)p*48*NPLANE + yx;
    #pragma unroll 4
    for (int c = 0; c < 48; ++c){
        lb[tid*50 + c] = bf16u(src[(size_t)c*NPLANE]);
    }
    __syncthreads();
    uint4* dst = (uint4*)(featT + (size_t)blockIdx.x*(256*48));
    #pragma unroll
    for (int m = 0; m < 6; ++m){
        const int u4 = tid + m*256;
        const int byteoff = u4*16;
        const int smp = byteoff/96;
        const int off = (byteoff%96) >> 2;
        const uint* rw = (const uint*)(lb + smp*50);
        uint4 val; val.x = rw[off]; val.y = rw[off+1]; val.z = rw[off+2]; val.w = rw[off+3];
        dst[u4] = val;
    }
}

// ---- wave-local MFMA layer, packed-B (coalesced 1KB wave-loads), in-place ----
template<int KSTEPS>
__device__ __forceinline__ void layer_w(unsigned short* Hw, const unsigned short* __restrict__ Wp,
                                        const float* sB, int lane, int ln31, int kg, const int* pr){
    f32x16 acc[4];
    #pragma unroll
    for (int nt=0;nt<4;++nt) acc[nt] = (f32x16)0.f;
    #pragma unroll
    for (int ks=0; ks<KSTEPS; ++ks){
        const int kb = ks*16 + kg*8;
        const short8 a = *reinterpret_cast<const short8*>(Hw + ln31*K0STR + kb);
        #pragma unroll
        for (int nt=0;nt<4;++nt){
            const short8 b = *reinterpret_cast<const short8*>(Wp + (((ks*4+nt)*64 + lane) << 3));
            acc[nt] = __builtin_amdgcn_mfma_f32_32x32x16_bf16(a, b, acc[nt], 0,0,0);
        }
    }
    #pragma unroll
    for (int nt=0;nt<4;++nt){
        #pragma unroll
        for (int r=0;r<16;++r){
            const int row = pr[r] >> 8;
            const int col = nt*32 + (pr[r] & 255);
            Hw[row*K0STR + col] = bf16u(fmaxf(acc[nt][r] + sB[col], 0.f));
        }
    }
}

// ---------------- fused kernel: 2 autonomous waves x 32 samples, zero barriers ----------------
__global__ __launch_bounds__(128) void nerf_mfma(
    const float* __restrict__ x, const float* __restrict__ d,
    const unsigned short* __restrict__ featT,
    const unsigned short* __restrict__ wp0, const unsigned short* __restrict__ wp1,
    const unsigned short* __restrict__ wp2,
    const float* __restrict__ b0, const float* __restrict__ b1, const float* __restrict__ b2,
    const float* __restrict__ W3, const float* __restrict__ b3,
    float* __restrict__ out)
{
    __shared__ unsigned short H[64*K0STR];   // 21504 B, wave w owns rows [w*32, w*32+32)
    __shared__ float  sBias[384];            // b0|b1|b2 (waves duplicate-write: benign)
    __shared__ float  sW3[516];              // W3 + b3

    const int tid  = threadIdx.x;
    const int wid  = tid >> 6, lane = tid & 63;
    const int ln31 = lane & 31, kg = lane >> 5;
    const int g0   = blockIdx.x * 64;
    const int sbase = wid * 32;
    unsigned short* Hw = H + sbase*K0STR;

    // ---- layout probes (register-only) ----
    short8 pa = {0,0,0,0,0,0,0,0}, pb = pa, qa = pa, qb = pa;
    if (kg == 0){
        pa[0] = (short)bf16u((float)ln31);
        pb[0] = (short)bf16u(1.0f);
        qa[0] = (short)bf16u(1.0f);
        qb[0] = (short)bf16u((float)ln31);
    }
    const f32x16 zz = (f32x16)0.f;
    const f32x16 D1 = __builtin_amdgcn_mfma_f32_32x32x16_bf16(pa, pb, zz, 0,0,0);
    const f32x16 D2 = __builtin_amdgcn_mfma_f32_32x32x16_bf16(qa, qb, zz, 0,0,0);
    int pr[16];
    #pragma unroll
    for (int r=0;r<16;++r) pr[r] = (((int)D1[r]) << 8) | (int)D2[r];

    // ---- stage biases + W3 ----
    for (int i = lane; i < 516; i += 64) sW3[i] = (i < 512) ? W3[i] : b3[i-512];
    for (int i = lane; i < 384; i += 64)
        sBias[i] = (i < 128) ? b0[i] : (i < 256) ? b1[i-128] : b2[i-256];

    // ---- PE(x,10): round0 (s32=ln31, m=kg), round1 lanes<32 m=2; lanes>=32 do PE(d) ----
    #pragma unroll
    for (int rr=0; rr<2; ++rr){
        int s32, m;
        if (rr == 0){ s32 = ln31; m = kg; }
        else {
            if (lane >= 32){
                const int k = lane - 32;
                if (k < 27){
                    const int ray = g0 >> 7;
                    float v;
                    if (k < 3) v = d[ray*3+k];
                    else {
                        const int l=(k-3)/6, r=(k-3)%6;
                        const float a = d[ray*3 + (r%3)] * (float)(1<<l);
                        v = (r<3)? sinf(a) : cosf(a);
                    }
                    const unsigned short bv = bf16u(v);
                    for (int s2=0;s2<32;++s2) H[(sbase+s2)*K0STR + 48 + k] = bv;
                }
                break;
            }
            s32 = lane; m = 2;
        }
        const int g = g0 + sbase + s32;
        const float xn = x[3*g+m]*(1.0f/3.0f);
        unsigned short* row = H + (sbase+s32)*K0STR;
        row[75+m] = bf16u(xn);
        float sv, cv;
        sincosf(xn, &sv, &cv);
        #pragma unroll
        for (int l=0;l<10;++l){
            row[78+l*6+m]   = bf16u(sv);
            row[78+l*6+3+m] = bf16u(cv);
            const float s2v = 2.0f*sv*cv;          // sin(2a)
            const float c2v = 1.0f - 2.0f*sv*sv;   // cos(2a)
            sv = s2v; cv = c2v;
        }
    }
    // zero-pad cols 138..143 (K padded to 144)
    if (lane < 32){
        uint* zr = (uint*)(H + (sbase+lane)*K0STR + 138);
        zr[0]=0u; zr[1]=0u; zr[2]=0u;
    }

    // ---- gather: units (s32, chunk), chunk-fastest; per-lane param recompute (no LDS) ----
    #pragma unroll
    for (int rr=0; rr<3; ++rr){
        const int u = rr*64 + lane;          // 0..191
        const int s32 = u/6, ch = u - s32*6;
        const int srow = sbase + s32;
        const int g = g0 + srow;
        const float xn0 = x[3*g+0]*(1.0f/3.0f);
        const float xn1 = x[3*g+1]*(1.0f/3.0f);
        const float xn2 = x[3*g+2]*(1.0f/3.0f);
        const int c0 = ch*8;
        float acc[8];
        #pragma unroll
        for (int q=0;q<8;++q) acc[q]=0.f;
        #pragma unroll
        for (int p=0;p<3;++p){
            const float gx = (p==1)? xn1 : xn0;
            const float gy = (p==0)? xn1 : xn2;
            const float ix = ((gx+1.0f)*0.5f)*511.0f;
            const float iy = ((gy+1.0f)*0.5f)*511.0f;
            const float fx0 = floorf(ix), fy0 = floorf(iy);
            const float wx1 = ix - fx0, wy1 = iy - fy0;
            const float wx0 = 1.0f-wx1, wy0 = 1.0f-wy1;
            const int x0i = (int)fx0, y0i = (int)fy0;
            const int x0c = min(max(x0i,0),511),   x1c = min(max(x0i+1,0),511);
            const int y0c = min(max(y0i,0),511),   y1c = min(max(y0i+1,0),511);
            const uint r0 = (uint)(p*NPLANE + y0c*512);
            const uint r1 = (uint)(p*NPLANE + y1c*512);
            const uint  av[4] = {(r0+x0c)*48u, (r0+x1c)*48u, (r1+x0c)*48u, (r1+x1c)*48u};
            const float wv[4] = {wx0*wy0, wx1*wy0, wx0*wy1, wx1*wy1};
            #pragma unroll
            for (int cr=0;cr<4;++cr){
                const uint4 uv = *(const uint4*)(featT + av[cr] + c0);
                const float w = wv[cr];
                acc[0]+=w*blo(uv.x); acc[1]+=w*bhi(uv.x);
                acc[2]+=w*blo(uv.y); acc[3]+=w*bhi(uv.y);
                acc[4]+=w*blo(uv.z); acc[5]+=w*bhi(uv.z);
                acc[6]+=w*blo(uv.w); acc[7]+=w*bhi(uv.w);
            }
        }
        union { unsigned short us[8]; uint4 v; } pk;
        #pragma unroll
        for (int q=0;q<8;++q) pk.us[q] = bf16u(acc[q]);
        *(uint4*)(H + srow*K0STR + c0) = pk.v;
    }

    // ---- MLP: 3 layers, wave-local, packed-B, in-place, no barriers ----
    layer_w<9>(Hw, wp0, sBias,       lane, ln31, kg, pr);   // K=144
    layer_w<8>(Hw, wp1, sBias + 128, lane, ln31, kg, pr);
    layer_w<8>(Hw, wp2, sBias + 256, lane, ln31, kg, pr);

    // ---- final layer 128->4 ----
    {
        const int s32 = lane >> 1, jp = (lane & 1)*2;
        const unsigned short* hrow = H + (sbase+s32)*K0STR;
        float a0 = sW3[512+jp], a1 = sW3[513+jp];
        #pragma unroll
        for (int q=0;q<16;++q){
            const uint4 u = *(const uint4*)(hrow + q*8);
            const int k = q*8;
            float h;
            h = blo(u.x); a0 += h*sW3[(k+0)*4+jp]; a1 += h*sW3[(k+0)*4+jp+1];
            h = bhi(u.x); a0 += h*sW3[(k+1)*4+jp]; a1 += h*sW3[(k+1)*4+jp+1];
            h = blo(u.y); a0 += h*sW3[(k+2)*4+jp]; a1 += h*sW3[(k+2)*4+jp+1];
            h = bhi(u.y); a0 += h*sW3[(k+3)*4+jp]; a1 += h*sW3[(k+3)*4+jp+1];
            h = blo(u.z); a0 += h*sW3[(k+4)*4+jp]; a1 += h*sW3[(k+4)*4+jp+1];
            h = bhi(u.z); a0 += h*sW3[(k+5)*4+jp]; a1 += h*sW3[(k+5)*4+jp+1];
            h = blo(u.w); a0 += h*sW3[(k+6)*4+jp]; a1 += h*sW3[(k+6)*4+jp+1];
            h = bhi(u.w); a0 += h*sW3[(k+7)*4+jp]; a1 += h*sW3[(k+7)*4+jp+1];
        }
        if (jp == 2) a1 = fmaxf(a1, 0.f);
        float2 o; o.x = a0; o.y = a1;
        *(float2*)(out + (size_t)(g0+sbase+s32)*4 + jp) = o;
    }
}

// ================= fallback (round-2 kernel, channel-major gather, fp32 MLP) =================
#define STR 148
#define SBLK 64
template<int K4, int KTAIL>
__device__ __forceinline__ void mlp_layer_fb(float (*Hs)[STR], const float* __restrict__ W,
                                             const float* __restrict__ B, int tid){
    const int tx = tid & 31, ty = tid >> 5;
    const int s0 = ty*8, j0 = tx*4;
    float acc[8][4];
    #pragma unroll
    for (int i=0;i<8;++i){ acc[i][0]=0.f; acc[i][1]=0.f; acc[i][2]=0.f; acc[i][3]=0.f; }
    for (int kk = 0; kk < K4; ++kk){
        const int k = kk*4;
        const float4 wa = *(const float4*)(W + (size_t)(k+0)*128 + j0);
        const float4 wb = *(const float4*)(W + (size_t)(k+1)*128 + j0);
        const float4 wc = *(const float4*)(W + (size_t)(k+2)*128 + j0);
        const float4 wd = *(const float4*)(W + (size_t)(k+3)*128 + j0);
        #pragma unroll
        for (int i=0;i<8;++i){
            const float4 h = *(const float4*)&Hs[s0+i][k];
            acc[i][0] += h.x*wa.x + h.y*wb.x + h.z*wc.x + h.w*wd.x;
            acc[i][1] += h.x*wa.y + h.y*wb.y + h.z*wc.y + h.w*wd.y;
            acc[i][2] += h.x*wa.z + h.y*wb.z + h.z*wc.z + h.w*wd.z;
            acc[i][3] += h.x*wa.w + h.y*wb.w + h.z*wc.w + h.w*wd.w;
        }
    }
    #pragma unroll
    for (int t=0;t<KTAIL;++t){
        const int k = K4*4+t;
        const float4 wa = *(const float4*)(W + (size_t)k*128 + j0);
        #pragma unroll
        for (int i=0;i<8;++i){
            const float h = Hs[s0+i][k];
            acc[i][0] += h*wa.x; acc[i][1] += h*wa.y; acc[i][2] += h*wa.z; acc[i][3] += h*wa.w;
        }
    }
    const float4 bb = *(const float4*)(B + j0);
    __syncthreads();
    #pragma unroll
    for (int i=0;i<8;++i){
        float4 o;
        o.x = fmaxf(acc[i][0]+bb.x, 0.f);
        o.y = fmaxf(acc[i][1]+bb.y, 0.f);
        o.z = fmaxf(acc[i][2]+bb.z, 0.f);
        o.w = fmaxf(acc[i][3]+bb.w, 0.f);
        *(float4*)&Hs[s0+i][j0] = o;
    }
    __syncthreads();
}

__global__ __launch_bounds__(256) void nerf_fused_fb(
    const float* __restrict__ x, const float* __restrict__ d,
    const float* __restrict__ feat,
    const float* __restrict__ W0, const float* __restrict__ b0,
    const float* __restrict__ W1, const float* __restrict__ b1,
    const float* __restrict__ W2, const float* __restrict__ b2,
    const float* __restrict__ W3, const float* __restrict__ b3,
    float* __restrict__ out)
{
    __shared__ float Hs[SBLK][STR];
    __shared__ uint4  sA[3][SBLK];
    __shared__ float4 sW[3][SBLK];

    const int tid = threadIdx.x;
    const int g0 = blockIdx.x * SBLK;

    if (tid < 192){
        const int s = tid & 63, p = tid >> 6;
        const int g = g0 + s;
        const float xn0 = x[3*g+0]/3.0f, xn1 = x[3*g+1]/3.0f, xn2 = x[3*g+2]/3.0f;
        const float gx = (p==1)? xn1 : xn0;
        const float gy = (p==0)? xn1 : xn2;
        const float ix = ((gx+1.0f)*0.5f)*511.0f;
        const float iy = ((gy+1.0f)*0.5f)*511.0f;
        const float fx0 = floorf(ix), fy0 = floorf(iy);
        const float wx1 = ix - fx0, wy1 = iy - fy0;
        const float wx0 = 1.0f-wx1, wy0 = 1.0f-wy1;
        const int x0i = (int)fx0, y0i = (int)fy0;
        const int x0c = min(max(x0i,0),511),   x1c = min(max(x0i+1,0),511);
        const int y0c = min(max(y0i,0),511),   y1c = min(max(y0i+1,0),511);
        const uint bp = (uint)p*48u*NPLANE;
        sA[p][s] = make_uint4(bp + y0c*512 + x0c, bp + y0c*512 + x1c,
                              bp + y1c*512 + x0c, bp + y1c*512 + x1c);
        sW[p][s] = make_float4(wx0*wy0, wx1*wy0, wx0*wy1, wx1*wy1);
    }
    if (tid < 64){
        const int s = tid, g = g0 + s;
        float xn[3];
        xn[0]=x[3*g+0]/3.0f; xn[1]=x[3*g+1]/3.0f; xn[2]=x[3*g+2]/3.0f;
        Hs[s][75]=xn[0]; Hs[s][76]=xn[1]; Hs[s][77]=xn[2];
        float f = 1.0f;
        for (int l=0;l<10;++l){
            #pragma unroll
            for (int m=0;m<3;++m){
                const float a = xn[m]*f;
                Hs[s][78+l*6+m]   = sinf(a);
                Hs[s][78+l*6+3+m] = cosf(a);
            }
            f *= 2.0f;
        }
    } else if (tid < 91){
        const int k = tid-64;
        const int ray = g0 >> 7;
        float v;
        if (k < 3) v = d[ray*3+k];
        else {
            const int l=(k-3)/6, r=(k-3)%6;
            const float a = d[ray*3 + (r%3)] * (float)(1<<l);
            v = (r<3)? sinf(a) : cosf(a);
        }
        for (int s2=0;s2<64;++s2) Hs[s2][48+k]=v;
    }
    __syncthreads();

    for (int it = tid; it < 384; it += 256){
        const int s = it & 63;
        const int c0 = (it >> 6)*8;
        float acc[8];
        #pragma unroll
        for (int q=0;q<8;++q) acc[q]=0.f;
        #pragma unroll
        for (int p=0;p<3;++p){
            const uint4  aa = sA[p][s];
            const float4 ww = sW[p][s];
            const uint  av[4] = {aa.x,aa.y,aa.z,aa.w};
            const float wv[4] = {ww.x,ww.y,ww.z,ww.w};
            #pragma unroll
            for (int cr=0;cr<4;++cr){
                const float w = wv[cr];
                const float* bsrc = feat + av[cr] + (size_t)c0*NPLANE;
                #pragma unroll
                for (int q=0;q<8;++q) acc[q] += w*bsrc[(size_t)q*NPLANE];
            }
        }
        *(float4*)&Hs[s][c0]   = make_float4(acc[0],acc[1],acc[2],acc[3]);
        *(float4*)&Hs[s][c0+4] = make_float4(acc[4],acc[5],acc[6],acc[7]);
    }
    __syncthreads();

    mlp_layer_fb<34,2>(Hs, W0, b0, tid);
    mlp_layer_fb<32,0>(Hs, W1, b1, tid);
    mlp_layer_fb<32,0>(Hs, W2, b2, tid);

    {
        const int s = tid>>2, j = tid&3;
        float acc = 0.f;
        for (int kk=0; kk<32; ++kk){
            const float4 h = *(const float4*)&Hs[s][kk*4];
            const int k = kk*4;
            acc += h.x*W3[(k+0)*4+j] + h.y*W3[(k+1)*4+j]
                 + h.z*W3[(k+2)*4+j] + h.w*W3[(k+3)*4+j];
        }
        acc += b3[j];
        if (j==3) acc = fmaxf(acc, 0.f);
        out[(size_t)blockIdx.x*256 + tid] = acc;
    }
}

extern "C" void kernel_launch(void* const* d_in, const int* in_sizes, int n_in,
                              void* d_out, int out_size, void* d_ws, size_t ws_size,
                              hipStream_t stream){
    (void)in_sizes; (void)n_in; (void)out_size;
    const float* x    = (const float*)d_in[0];
    const float* ddir = (const float*)d_in[1];
    const float* feat = (const float*)d_in[2];
    const float* W0 = (const float*)d_in[3];  const float* b0 = (const float*)d_in[4];
    const float* W1 = (const float*)d_in[5];  const float* b1 = (const float*)d_in[6];
    const float* W2 = (const float*)d_in[7];  const float* b2 = (const float*)d_in[8];
    const float* W3 = (const float*)d_in[9];  const float* b3 = (const float*)d_in[10];
    float* out = (float*)d_out;

    const size_t needAll = (size_t)WS_FEAT_BYTE + (size_t)3*NPLANE*48*2;
    if (ws_size >= needAll){
        unsigned short* wsu   = (unsigned short*)d_ws;
        unsigned short* featT = (unsigned short*)((char*)d_ws + WS_FEAT_BYTE);
        prep_weights<<<200, 256, 0, stream>>>(W0, W1, W2, wsu);
        transpose_feat_k<<<3072, 256, 0, stream>>>(feat, featT);
        nerf_mfma<<<8192, 128, 0, stream>>>(x, ddir, featT,
                                            wsu + P0_OFF, wsu + P1_OFF, wsu + P2_OFF,
                                            b0, b1, b2, W3, b3, out);
    } else {
        nerf_fused_fb<<<8192, 256, 0, stream>>>(x, ddir, feat,
                                                W0,b0,W1,b1,W2,b2,W3,b3, out);
    }
}

// Round 8
// 271.851 us; speedup vs baseline: 3.3614x; 1.1255x over previous
//
#include <hip/hip_runtime.h>
#include <hip/hip_bf16.h>
#include <cstdint>
#include <cstddef>

#define NPLANE 262144      // 512*512
#define HSTR 152           // H row stride (bf16 elems) = 304B; %32-word=12 -> 4-way spread
#define WS_FEAT_BYTE 131072
#define PW_LAYER 18432     // shorts per packed layer (9 ksteps x 4 nt x 64 lanes x 8)

typedef unsigned int uint;
typedef __attribute__((ext_vector_type(16))) float f32x16;
typedef __attribute__((ext_vector_type(8))) short short8;

__device__ __forceinline__ float blo(uint u){ union{uint i; float f;} v; v.i = u<<16; return v.f; }
__device__ __forceinline__ float bhi(uint u){ union{uint i; float f;} v; v.i = u & 0xffff0000u; return v.f; }
__device__ __forceinline__ unsigned short bf16u(float f){
    __hip_bfloat16 h = __float2bfloat16(f);
    return *reinterpret_cast<unsigned short*>(&h);
}
__device__ __forceinline__ f32x16 mfma_(short8 a, short8 b, f32x16 c){
    return __builtin_amdgcn_mfma_f32_32x32x16_bf16(a, b, c, 0,0,0);
}

// ---- weight prepass: W[K][N] fp32 -> fragment-packed bf16, bias folded as row K ----
// packed idx = ((ks*4+nt)*64 + lane)*8 + e ; k = ks*16 + (lane>>5)*8 + e ; n = nt*32 + (lane&31)
// value: k<KREAL -> W[k][n]; k==KREAL -> bias[n]; else 0.   (L0 KREAL=138, L1/2 KREAL=128)
__global__ __launch_bounds__(256) void prep_weights(const float* __restrict__ W0,
                                                    const float* __restrict__ W1,
                                                    const float* __restrict__ W2,
                                                    const float* __restrict__ b0,
                                                    const float* __restrict__ b1,
                                                    const float* __restrict__ b2,
                                                    unsigned short* __restrict__ ws){
    const int idx = blockIdx.x*256 + threadIdx.x;
    if (idx >= 3*PW_LAYER) return;
    const int L = idx / PW_LAYER, base = idx % PW_LAYER;
    const float* W = (L==0)? W0 : (L==1)? W1 : W2;
    const float* B = (L==0)? b0 : (L==1)? b1 : b2;
    const int KREAL = (L==0)? 138 : 128;
    const int e  = base & 7;
    const int l  = (base >> 3) & 63;
    const int fr = base >> 9;
    const int ks = fr >> 2, nt = fr & 3;
    const int k  = ks*16 + (l >> 5)*8 + e;
    const int n  = nt*32 + (l & 31);
    float v = 0.f;
    if (k < KREAL) v = W[k*128 + n];
    else if (k == KREAL) v = B[n];
    ws[idx] = bf16u(v);
}

// ---------------- transpose feat (3,48,512,512) fp32 -> (3,512,512,48) bf16 ----------------
__global__ __launch_bounds__(256) void transpose_feat_k(const float* __restrict__ feat,
                                                        unsigned short* __restrict__ featT){
    __shared__ unsigned short lb[256*50];
    const int tid = threadIdx.x;
    const int pos = blockIdx.x*256 + tid;
    const int p  = pos >> 18;
    const int yx = pos & (NPLANE-1);
    const float* src = feat + (size_t)p*48*NPLANE + yx;
    #pragma unroll 4
    for (int c = 0; c < 48; ++c){
        lb[tid*50 + c] = bf16u(src[(size_t)c*NPLANE]);
    }
    __syncthreads();
    uint4* dst = (uint4*)(featT + (size_t)blockIdx.x*(256*48));
    #pragma unroll
    for (int m = 0; m < 6; ++m){
        const int u4 = tid + m*256;
        const int byteoff = u4*16;
        const int smp = byteoff/96;
        const int off = (byteoff%96) >> 2;
        const uint* rw = (const uint*)(lb + smp*50);
        uint4 val; val.x = rw[off]; val.y = rw[off+1]; val.z = rw[off+2]; val.w = rw[off+3];
        dst[u4] = val;
    }
}

// ---- one MLP layer (9 ksteps, bias in matmul), N-halves with batched B-loads ----
__device__ __forceinline__ void run_layer(unsigned short* H, const unsigned short* __restrict__ Wp,
                                          int lane, int ln31, int kg, const int* pr){
    const unsigned short* Hrow = H + ln31*HSTR;
    f32x16 acc[4];
    #pragma unroll
    for (int i=0;i<4;++i) acc[i] = (f32x16)0.f;
    #pragma unroll
    for (int h=0; h<2; ++h){
        short8 bf[10];
        // chunk A: ks 0..4 (10 batched loads)
        #pragma unroll
        for (int i=0;i<10;++i){
            const int ks = i>>1, nt = 2*h + (i&1);
            bf[i] = *reinterpret_cast<const short8*>(Wp + (((ks*4+nt)*64 + lane) << 3));
        }
        #pragma unroll
        for (int ks=0; ks<5; ++ks){
            const short8 a = *reinterpret_cast<const short8*>(Hrow + ks*16 + kg*8);
            acc[2*h]   = mfma_(a, bf[2*ks],   acc[2*h]);
            acc[2*h+1] = mfma_(a, bf[2*ks+1], acc[2*h+1]);
        }
        // chunk B: ks 5..8 (8 batched loads)
        #pragma unroll
        for (int i=0;i<8;++i){
            const int ks = 5 + (i>>1), nt = 2*h + (i&1);
            bf[i] = *reinterpret_cast<const short8*>(Wp + (((ks*4+nt)*64 + lane) << 3));
        }
        #pragma unroll
        for (int ks=5; ks<9; ++ks){
            const short8 a = *reinterpret_cast<const short8*>(Hrow + ks*16 + kg*8);
            acc[2*h]   = mfma_(a, bf[2*(ks-5)],   acc[2*h]);
            acc[2*h+1] = mfma_(a, bf[2*(ks-5)+1], acc[2*h+1]);
        }
    }
    // deferred epilogue (in-place safe: all A-reads done)
    #pragma unroll
    for (int nt=0;nt<4;++nt){
        #pragma unroll
        for (int r=0;r<16;++r){
            const int row = pr[r] >> 8;
            const int col = nt*32 + (pr[r] & 255);
            H[row*HSTR + col] = bf16u(fmaxf(acc[nt][r], 0.f));
        }
    }
}

// ---------------- fused kernel: 1 wave per block, 32 samples, zero barriers ----------------
__global__ __launch_bounds__(64, 4) void nerf_mfma(
    const float* __restrict__ x, const float* __restrict__ d,
    const unsigned short* __restrict__ featT,
    const unsigned short* __restrict__ wp0, const unsigned short* __restrict__ wp1,
    const unsigned short* __restrict__ wp2,
    const float* __restrict__ W3, const float* __restrict__ b3,
    float* __restrict__ out)
{
    __shared__ unsigned short H[32*HSTR];    // 9728 B
    __shared__ uint sW3u[256];               // W3 bf16 pairs: [k][colpair] -> 1024 B

    const int lane = threadIdx.x;            // 0..63
    const int ln31 = lane & 31, kg = lane >> 5;
    const int g0 = blockIdx.x * 32;

    // ---- layout probes (register-only) ----
    short8 pa = {0,0,0,0,0,0,0,0}, pb = pa, qa = pa, qb = pa;
    if (kg == 0){
        pa[0] = (short)bf16u((float)ln31);
        pb[0] = (short)bf16u(1.0f);
        qa[0] = (short)bf16u(1.0f);
        qb[0] = (short)bf16u((float)ln31);
    }
    const f32x16 zz = (f32x16)0.f;
    const f32x16 D1 = __builtin_amdgcn_mfma_f32_32x32x16_bf16(pa, pb, zz, 0,0,0);
    const f32x16 D2 = __builtin_amdgcn_mfma_f32_32x32x16_bf16(qa, qb, zz, 0,0,0);
    int pr[16];
    #pragma unroll
    for (int r=0;r<16;++r) pr[r] = (((int)D1[r]) << 8) | (int)D2[r];

    // ---- stage W3 as bf16 pairs: sW3u[k*2+c] = (W3[k][2c], W3[k][2c+1]) ----
    #pragma unroll
    for (int j=0;j<4;++j){
        const int idx = lane*4 + j;          // 0..255
        const int k = idx >> 1, c = idx & 1;
        sW3u[idx] = ((uint)bf16u(W3[k*4 + 2*c])) | (((uint)bf16u(W3[k*4 + 2*c + 1])) << 16);
    }

    // ---- PE(x,10): rr0 (s=ln31, m=kg); rr1 lanes<32 m=2, lanes>=32 do PE(d) ----
    #pragma unroll
    for (int rr=0; rr<2; ++rr){
        int s32, m;
        if (rr == 0){ s32 = ln31; m = kg; }
        else {
            if (lane >= 32){
                const int k = lane - 32;
                if (k < 27){
                    const int ray = g0 >> 7;
                    float v;
                    if (k < 3) v = d[ray*3+k];
                    else {
                        const int l=(k-3)/6, r=(k-3)%6;
                        const float a = d[ray*3 + (r%3)] * (float)(1<<l);
                        v = (r<3)? sinf(a) : cosf(a);
                    }
                    const unsigned short bv = bf16u(v);
                    for (int s2=0;s2<32;++s2) H[s2*HSTR + 48 + k] = bv;
                }
                break;
            }
            s32 = lane; m = 2;
        }
        const int g = g0 + s32;
        const float xn = x[3*g+m]*(1.0f/3.0f);
        unsigned short* row = H + s32*HSTR;
        row[75+m] = bf16u(xn);
        float sv, cv;
        sincosf(xn, &sv, &cv);
        #pragma unroll
        for (int l=0;l<10;++l){
            row[78+l*6+m]   = bf16u(sv);
            row[78+l*6+3+m] = bf16u(cv);
            const float s2v = 2.0f*sv*cv;
            const float c2v = 1.0f - 2.0f*sv*sv;
            sv = s2v; cv = c2v;
        }
    }
    // pad cols 138..143: col138 = 1.0 (bias slot for L0), rest 0
    if (lane < 32){
        *(uint*)(H + lane*HSTR + 138)  = 0x00003f80u;
        *(uint2*)(H + lane*HSTR + 140) = make_uint2(0u, 0u);
    }

    // ---- gather -> cols [0..47]; units (s32, chunk) chunk-fastest ----
    #pragma unroll
    for (int rr=0; rr<3; ++rr){
        const int u = rr*64 + lane;          // 0..191
        const int s32 = u/6, ch = u - s32*6;
        const int g = g0 + s32;
        const float xn0 = x[3*g+0]*(1.0f/3.0f);
        const float xn1 = x[3*g+1]*(1.0f/3.0f);
        const float xn2 = x[3*g+2]*(1.0f/3.0f);
        const int c0 = ch*8;
        float acc[8];
        #pragma unroll
        for (int q=0;q<8;++q) acc[q]=0.f;
        #pragma unroll
        for (int p=0;p<3;++p){
            const float gx = (p==1)? xn1 : xn0;
            const float gy = (p==0)? xn1 : xn2;
            const float ix = ((gx+1.0f)*0.5f)*511.0f;
            const float iy = ((gy+1.0f)*0.5f)*511.0f;
            const float fx0 = floorf(ix), fy0 = floorf(iy);
            const float wx1 = ix - fx0, wy1 = iy - fy0;
            const float wx0 = 1.0f-wx1, wy0 = 1.0f-wy1;
            const int x0i = (int)fx0, y0i = (int)fy0;
            const int x0c = min(max(x0i,0),511),   x1c = min(max(x0i+1,0),511);
            const int y0c = min(max(y0i,0),511),   y1c = min(max(y0i+1,0),511);
            const uint r0 = (uint)(p*NPLANE + y0c*512);
            const uint r1 = (uint)(p*NPLANE + y1c*512);
            const uint  av[4] = {(r0+x0c)*48u, (r0+x1c)*48u, (r1+x0c)*48u, (r1+x1c)*48u};
            const float wv[4] = {wx0*wy0, wx1*wy0, wx0*wy1, wx1*wy1};
            #pragma unroll
            for (int cr=0;cr<4;++cr){
                const uint4 uv = *(const uint4*)(featT + av[cr] + c0);
                const float w = wv[cr];
                acc[0]+=w*blo(uv.x); acc[1]+=w*bhi(uv.x);
                acc[2]+=w*blo(uv.y); acc[3]+=w*bhi(uv.y);
                acc[4]+=w*blo(uv.z); acc[5]+=w*bhi(uv.z);
                acc[6]+=w*blo(uv.w); acc[7]+=w*bhi(uv.w);
            }
        }
        union { unsigned short us[8]; uint4 v; } pk;
        #pragma unroll
        for (int q=0;q<8;++q) pk.us[q] = bf16u(acc[q]);
        *(uint4*)(H + s32*HSTR + c0) = pk.v;
    }

    // ---- MLP (bias folded; all layers 9 ksteps) ----
    run_layer(H, wp0, lane, ln31, kg, pr);
    // rewrite cols 128..143 -> [1, 0...] (bias slot for L1/L2)
    if (lane < 32) *(uint4*)(H + lane*HSTR + 128) = make_uint4(0x00003f80u,0u,0u,0u);
    else           *(uint4*)(H + ln31*HSTR + 136) = make_uint4(0u,0u,0u,0u);
    run_layer(H, wp1, lane, ln31, kg, pr);
    run_layer(H, wp2, lane, ln31, kg, pr);

    // ---- final layer 128->4 (bf16 W3 pairs from LDS, b3 from global) ----
    {
        const int s32 = lane >> 1, cp = lane & 1;    // cp: column pair (0: j0,1; 1: j2,3)
        const unsigned short* hrow = H + s32*HSTR;
        const float2 b3v = *(const float2*)(b3 + 2*cp);
        float a0 = b3v.x, a1 = b3v.y;
        #pragma unroll
        for (int q=0;q<16;++q){
            const uint4 u = *(const uint4*)(hrow + q*8);
            const int k = q*8;
            float h; uint wp_;
            h = blo(u.x); wp_ = sW3u[(k+0)*2+cp]; a0 += h*blo(wp_); a1 += h*bhi(wp_);
            h = bhi(u.x); wp_ = sW3u[(k+1)*2+cp]; a0 += h*blo(wp_); a1 += h*bhi(wp_);
            h = blo(u.y); wp_ = sW3u[(k+2)*2+cp]; a0 += h*blo(wp_); a1 += h*bhi(wp_);
            h = bhi(u.y); wp_ = sW3u[(k+3)*2+cp]; a0 += h*blo(wp_); a1 += h*bhi(wp_);
            h = blo(u.z); wp_ = sW3u[(k+4)*2+cp]; a0 += h*blo(wp_); a1 += h*bhi(wp_);
            h = bhi(u.z); wp_ = sW3u[(k+5)*2+cp]; a0 += h*blo(wp_); a1 += h*bhi(wp_);
            h = blo(u.w); wp_ = sW3u[(k+6)*2+cp]; a0 += h*blo(wp_); a1 += h*bhi(wp_);
            h = bhi(u.w); wp_ = sW3u[(k+7)*2+cp]; a0 += h*blo(wp_); a1 += h*bhi(wp_);
        }
        if (cp == 1) a1 = fmaxf(a1, 0.f);    // j==3 relu
        float2 o; o.x = a0; o.y = a1;
        *(float2*)(out + (size_t)(g0+s32)*4 + 2*cp) = o;
    }
}

// ================= fallback (round-2 kernel, channel-major gather, fp32 MLP) =================
#define STR 148
#define SBLK 64
template<int K4, int KTAIL>
__device__ __forceinline__ void mlp_layer_fb(float (*Hs)[STR], const float* __restrict__ W,
                                             const float* __restrict__ B, int tid){
    const int tx = tid & 31, ty = tid >> 5;
    const int s0 = ty*8, j0 = tx*4;
    float acc[8][4];
    #pragma unroll
    for (int i=0;i<8;++i){ acc[i][0]=0.f; acc[i][1]=0.f; acc[i][2]=0.f; acc[i][3]=0.f; }
    for (int kk = 0; kk < K4; ++kk){
        const int k = kk*4;
        const float4 wa = *(const float4*)(W + (size_t)(k+0)*128 + j0);
        const float4 wb = *(const float4*)(W + (size_t)(k+1)*128 + j0);
        const float4 wc = *(const float4*)(W + (size_t)(k+2)*128 + j0);
        const float4 wd = *(const float4*)(W + (size_t)(k+3)*128 + j0);
        #pragma unroll
        for (int i=0;i<8;++i){
            const float4 h = *(const float4*)&Hs[s0+i][k];
            acc[i][0] += h.x*wa.x + h.y*wb.x + h.z*wc.x + h.w*wd.x;
            acc[i][1] += h.x*wa.y + h.y*wb.y + h.z*wc.y + h.w*wd.y;
            acc[i][2] += h.x*wa.z + h.y*wb.z + h.z*wc.z + h.w*wd.z;
            acc[i][3] += h.x*wa.w + h.y*wb.w + h.z*wc.w + h.w*wd.w;
        }
    }
    #pragma unroll
    for (int t=0;t<KTAIL;++t){
        const int k = K4*4+t;
        const float4 wa = *(const float4*)(W + (size_t)k*128 + j0);
        #pragma unroll
        for (int i=0;i<8;++i){
            const float h = Hs[s0+i][k];
            acc[i][0] += h*wa.x; acc[i][1] += h*wa.y; acc[i][2] += h*wa.z; acc[i][3] += h*wa.w;
        }
    }
    const float4 bb = *(const float4*)(B + j0);
    __syncthreads();
    #pragma unroll
    for (int i=0;i<8;++i){
        float4 o;
        o.x = fmaxf(acc[i][0]+bb.x, 0.f);
        o.y = fmaxf(acc[i][1]+bb.y, 0.f);
        o.z = fmaxf(acc[i][2]+bb.z, 0.f);
        o.w = fmaxf(acc[i][3]+bb.w, 0.f);
        *(float4*)&Hs[s0+i][j0] = o;
    }
    __syncthreads();
}

__global__ __launch_bounds__(256) void nerf_fused_fb(
    const float* __restrict__ x, const float* __restrict__ d,
    const float* __restrict__ feat,
    const float* __restrict__ W0, const float* __restrict__ b0,
    const float* __restrict__ W1, const float* __restrict__ b1,
    const float* __restrict__ W2, const float* __restrict__ b2,
    const float* __restrict__ W3, const float* __restrict__ b3,
    float* __restrict__ out)
{
    __shared__ float Hs[SBLK][STR];
    __shared__ uint4  sA[3][SBLK];
    __shared__ float4 sW[3][SBLK];

    const int tid = threadIdx.x;
    const int g0 = blockIdx.x * SBLK;

    if (tid < 192){
        const int s = tid & 63, p = tid >> 6;
        const int g = g0 + s;
        const float xn0 = x[3*g+0]/3.0f, xn1 = x[3*g+1]/3.0f, xn2 = x[3*g+2]/3.0f;
        const float gx = (p==1)? xn1 : xn0;
        const float gy = (p==0)? xn1 : xn2;
        const float ix = ((gx+1.0f)*0.5f)*511.0f;
        const float iy = ((gy+1.0f)*0.5f)*511.0f;
        const float fx0 = floorf(ix), fy0 = floorf(iy);
        const float wx1 = ix - fx0, wy1 = iy - fy0;
        const float wx0 = 1.0f-wx1, wy0 = 1.0f-wy1;
        const int x0i = (int)fx0, y0i = (int)fy0;
        const int x0c = min(max(x0i,0),511),   x1c = min(max(x0i+1,0),511);
        const int y0c = min(max(y0i,0),511),   y1c = min(max(y0i+1,0),511);
        const uint bp = (uint)p*48u*NPLANE;
        sA[p][s] = make_uint4(bp + y0c*512 + x0c, bp + y0c*512 + x1c,
                              bp + y1c*512 + x0c, bp + y1c*512 + x1c);
        sW[p][s] = make_float4(wx0*wy0, wx1*wy0, wx0*wy1, wx1*wy1);
    }
    if (tid < 64){
        const int s = tid, g = g0 + s;
        float xn[3];
        xn[0]=x[3*g+0]/3.0f; xn[1]=x[3*g+1]/3.0f; xn[2]=x[3*g+2]/3.0f;
        Hs[s][75]=xn[0]; Hs[s][76]=xn[1]; Hs[s][77]=xn[2];
        float f = 1.0f;
        for (int l=0;l<10;++l){
            #pragma unroll
            for (int m=0;m<3;++m){
                const float a = xn[m]*f;
                Hs[s][78+l*6+m]   = sinf(a);
                Hs[s][78+l*6+3+m] = cosf(a);
            }
            f *= 2.0f;
        }
    } else if (tid < 91){
        const int k = tid-64;
        const int ray = g0 >> 7;
        float v;
        if (k < 3) v = d[ray*3+k];
        else {
            const int l=(k-3)/6, r=(k-3)%6;
            const float a = d[ray*3 + (r%3)] * (float)(1<<l);
            v = (r<3)? sinf(a) : cosf(a);
        }
        for (int s2=0;s2<64;++s2) Hs[s2][48+k]=v;
    }
    __syncthreads();

    for (int it = tid; it < 384; it += 256){
        const int s = it & 63;
        const int c0 = (it >> 6)*8;
        float acc[8];
        #pragma unroll
        for (int q=0;q<8;++q) acc[q]=0.f;
        #pragma unroll
        for (int p=0;p<3;++p){
            const uint4  aa = sA[p][s];
            const float4 ww = sW[p][s];
            const uint  av[4] = {aa.x,aa.y,aa.z,aa.w};
            const float wv[4] = {ww.x,ww.y,ww.z,ww.w};
            #pragma unroll
            for (int cr=0;cr<4;++cr){
                const float w = wv[cr];
                const float* bsrc = feat + av[cr] + (size_t)c0*NPLANE;
                #pragma unroll
                for (int q=0;q<8;++q) acc[q] += w*bsrc[(size_t)q*NPLANE];
            }
        }
        *(float4*)&Hs[s][c0]   = make_float4(acc[0],acc[1],acc[2],acc[3]);
        *(float4*)&Hs[s][c0+4] = make_float4(acc[4],acc[5],acc[6],acc[7]);
    }
    __syncthreads();

    mlp_layer_fb<34,2>(Hs, W0, b0, tid);
    mlp_layer_fb<32,0>(Hs, W1, b1, tid);
    mlp_layer_fb<32,0>(Hs, W2, b2, tid);

    {
        const int s = tid>>2, j = tid&3;
        float acc = 0.f;
        for (int kk=0; kk<32; ++kk){
            const float4 h = *(const float4*)&Hs[s][kk*4];
            const int k = kk*4;
            acc += h.x*W3[(k+0)*4+j] + h.y*W3[(k+1)*4+j]
                 + h.z*W3[(k+2)*4+j] + h.w*W3[(k+3)*4+j];
        }
        acc += b3[j];
        if (j==3) acc = fmaxf(acc, 0.f);
        out[(size_t)blockIdx.x*256 + tid] = acc;
    }
}

extern "C" void kernel_launch(void* const* d_in, const int* in_sizes, int n_in,
                              void* d_out, int out_size, void* d_ws, size_t ws_size,
                              hipStream_t stream){
    (void)in_sizes; (void)n_in; (void)out_size;
    const float* x    = (const float*)d_in[0];
    const float* ddir = (const float*)d_in[1];
    const float* feat = (const float*)d_in[2];
    const float* W0 = (const float*)d_in[3];  const float* b0 = (const float*)d_in[4];
    const float* W1 = (const float*)d_in[5];  const float* b1 = (const float*)d_in[6];
    const float* W2 = (const float*)d_in[7];  const float* b2 = (const float*)d_in[8];
    const float* W3 = (const float*)d_in[9];  const float* b3 = (const float*)d_in[10];
    float* out = (float*)d_out;

    const size_t needAll = (size_t)WS_FEAT_BYTE + (size_t)3*NPLANE*48*2;
    if (ws_size >= needAll){
        unsigned short* wsu   = (unsigned short*)d_ws;
        unsigned short* featT = (unsigned short*)((char*)d_ws + WS_FEAT_BYTE);
        prep_weights<<<216, 256, 0, stream>>>(W0, W1, W2, b0, b1, b2, wsu);
        transpose_feat_k<<<3072, 256, 0, stream>>>(feat, featT);
        nerf_mfma<<<16384, 64, 0, stream>>>(x, ddir, featT,
                                            wsu, wsu + PW_LAYER, wsu + 2*PW_LAYER,
                                            W3, b3, out);
    } else {
        nerf_fused_fb<<<8192, 256, 0, stream>>>(x, ddir, feat,
                                                W0,b0,W1,b1,W2,b2,W3,b3, out);
    }
}